// Round 1
// baseline (628.658 us; speedup 1.0000x reference)
//
#include <hip/hip_runtime.h>
#include <math.h>

#define LN_EPS 1e-5f

// ws layout (float offsets)
#define WS_QP   0            // q_p * scale (128)
#define WS_V0   128          // v0 (128)
#define WS_S0   256          // s0 scalar
#define WS_H1P  512          // 16*256 h1 partials
#define WS_PART (512 + 4096) // per-block partials: [m, l, acc[128]] stride 130
#define PART_STRIDE 130

__device__ __forceinline__ float elu1(float x){ return x > 0.f ? x : expm1f(x); }

// ---------------- K0: h1 partial dots (parallelize W1 load over 16 CUs) ----------------
__global__ __launch_bounds__(256) void k_h1(const float* __restrict__ x,
    const float* __restrict__ W1, int d_omic, float* __restrict__ ws)
{
  int g = blockIdx.x, tid = threadIdx.x;
  int i0 = g * 99, i1 = min(i0 + 99, d_omic);
  __shared__ float xs[112];
  for (int i = i0 + tid; i < i1; i += 256) xs[i - i0] = x[i];
  __syncthreads();
  float s = 0.f;
  for (int i = i0; i < i1; i++) s = fmaf(xs[i - i0], W1[(size_t)i * 256 + tid], s);
  ws[WS_H1P + g * 256 + tid] = s;
}

// ---------------- K1: omic MLP + token0 LN1 + q_p/k_p/v0 + s0 ----------------
__global__ __launch_bounds__(256) void k_omic(
    const float* __restrict__ b1,
    const float* __restrict__ W2, const float* __restrict__ b2,
    const float* __restrict__ Wqkv,
    const float* __restrict__ ln1_g, const float* __restrict__ ln1_b,
    float* __restrict__ ws)
{
  __shared__ float h1[256];
  __shared__ float xn0[256];
  __shared__ float qs[128], ks[128];
  __shared__ float red[8];
  int tid = threadIdx.x, lane = tid & 63, wave = tid >> 6;

  float s = b1[tid];
  for (int g = 0; g < 16; g++) s += ws[WS_H1P + g * 256 + tid];
  h1[tid] = elu1(s);
  __syncthreads();

  s = b2[tid];
  for (int i = 0; i < 256; i++) s = fmaf(h1[i], W2[i * 256 + tid], s);
  float t0 = elu1(s);

  float ps = t0, pq = t0 * t0;
  for (int m = 1; m < 64; m <<= 1) { ps += __shfl_xor(ps, m); pq += __shfl_xor(pq, m); }
  if (lane == 0) { red[wave] = ps; red[4 + wave] = pq; }
  __syncthreads();
  float mu = (red[0] + red[1] + red[2] + red[3]) * (1.f / 256.f);
  float var = (red[4] + red[5] + red[6] + red[7]) * (1.f / 256.f) - mu * mu;
  float xn = (t0 - mu) * rsqrtf(var + LN_EPS) * ln1_g[tid] + ln1_b[tid];
  xn0[tid] = xn;
  __syncthreads();

  float a = 0.f;
  for (int j = 0; j < 256; j++) a = fmaf(xn0[j], Wqkv[j * 384 + tid], a);
  if (tid < 128) { float q = a * 0.088388347648318447f; qs[tid] = q; ws[WS_QP + tid] = q; }
  else           { ks[tid - 128] = a; }
  if (tid < 128) {
    float av = 0.f;
    for (int j = 0; j < 256; j++) av = fmaf(xn0[j], Wqkv[j * 384 + 256 + tid], av);
    ws[WS_V0 + tid] = av;
  }
  __syncthreads();
  float p = (tid < 128) ? qs[tid] * ks[tid] : 0.f;
  for (int m = 1; m < 64; m <<= 1) p += __shfl_xor(p, m);
  if (lane == 0) red[wave] = p;
  __syncthreads();
  if (tid == 0) ws[WS_S0] = red[0] + red[1] + red[2] + red[3];
}

// ---------------- K2: fused wsi@Wp+bp -> LN1 -> k,v -> scores -> online-softmax partials ----
__global__ __launch_bounds__(256, 2) void k_main(
    const float* __restrict__ wsi, int N,
    const float* __restrict__ Wp, const float* __restrict__ bp,
    const float* __restrict__ ln1_g, const float* __restrict__ ln1_b,
    const float* __restrict__ Wqkv,
    float* __restrict__ ws)
{
  __shared__ __align__(16) float smem[16384];       // 64 KiB, phase-unioned
  float* As = smem;                                  // [32][68] A transposed, padded
  float* Bs = smem + 32 * 68;                        // [32][256]
  float* XT = smem;                                  // [256][64] xn transposed (swizzled)
  float* scores = smem;                              // [64]
  float* red = smem + 64;                            // [16][128]

  const int tid = threadIdx.x;
  const int rg = tid >> 4, cg = tid & 15;            // thread tile: 4 rows x 16 cols
  const int b = blockIdx.x;
  const int r0 = b * 64;

  float acc[4][16];
  #pragma unroll
  for (int i = 0; i < 4; i++)
    #pragma unroll
    for (int m = 0; m < 16; m++) acc[i][m] = 0.f;

  const int arow0 = tid >> 3;          // 0..31
  const int akidx = (tid & 7) << 2;    // 0,4,...,28

  // ---- phase 1: T = wsi[r0:r0+64] @ Wp ----
  for (int kk = 0; kk < 1024; kk += 32) {
    #pragma unroll
    for (int p = 0; p < 2; p++) {
      int row = arow0 + p * 32;
      int gr = r0 + row;
      float4 a4 = make_float4(0.f, 0.f, 0.f, 0.f);
      if (gr < N) a4 = *(const float4*)&wsi[(size_t)gr * 1024 + kk + akidx];
      As[(akidx + 0) * 68 + row] = a4.x;
      As[(akidx + 1) * 68 + row] = a4.y;
      As[(akidx + 2) * 68 + row] = a4.z;
      As[(akidx + 3) * 68 + row] = a4.w;
    }
    {
      int kb = tid >> 6;               // 0..3
      int colb = (tid & 63) << 2;      // 0..252
      #pragma unroll
      for (int p = 0; p < 8; p++) {
        int k = p * 4 + kb;
        *(float4*)&Bs[k * 256 + colb] = *(const float4*)&Wp[(size_t)(kk + k) * 256 + colb];
      }
    }
    __syncthreads();
    #pragma unroll 4
    for (int k = 0; k < 32; k++) {
      float4 a4 = *(float4*)&As[k * 68 + (rg << 2)];
      float av[4] = {a4.x, a4.y, a4.z, a4.w};
      #pragma unroll
      for (int q = 0; q < 4; q++) {
        float4 b4 = *(float4*)&Bs[k * 256 + (cg << 2) + (q << 6)];
        float bv[4] = {b4.x, b4.y, b4.z, b4.w};
        #pragma unroll
        for (int i = 0; i < 4; i++)
          #pragma unroll
          for (int j = 0; j < 4; j++)
            acc[i][q * 4 + j] = fmaf(av[i], bv[j], acc[i][q * 4 + j]);
      }
    }
    __syncthreads();
  }

  // ---- bias + LN1 (row stats via shfl across the 16 cg lanes) ----
  float psum[4] = {0, 0, 0, 0}, psq[4] = {0, 0, 0, 0};
  #pragma unroll
  for (int m = 0; m < 16; m++) {
    int col = ((m >> 2) << 6) + (cg << 2) + (m & 3);
    float bpv = bp[col];
    #pragma unroll
    for (int i = 0; i < 4; i++) {
      float v = acc[i][m] + bpv;
      acc[i][m] = v;
      psum[i] += v; psq[i] += v * v;
    }
  }
  #pragma unroll
  for (int m = 1; m < 16; m <<= 1) {
    #pragma unroll
    for (int i = 0; i < 4; i++) { psum[i] += __shfl_xor(psum[i], m); psq[i] += __shfl_xor(psq[i], m); }
  }
  float mu4[4], rs4[4];
  #pragma unroll
  for (int i = 0; i < 4; i++) {
    mu4[i] = psum[i] * (1.f / 256.f);
    float var = psq[i] * (1.f / 256.f) - mu4[i] * mu4[i];
    rs4[i] = rsqrtf(var + LN_EPS);
  }
  // write xn transposed into XT with 4-row-block rotation swizzle (conflict-reduced)
  #pragma unroll
  for (int m = 0; m < 16; m++) {
    int col = ((m >> 2) << 6) + (cg << 2) + (m & 3);
    float gvv = ln1_g[col], bvv = ln1_b[col];
    #pragma unroll
    for (int i = 0; i < 4; i++) {
      int r = (rg << 2) + i;
      float xnv = (acc[i][m] - mu4[i]) * rs4[i] * gvv + bvv;
      XT[col * 64 + ((r + (col << 2)) & 63)] = xnv;
    }
  }
  __syncthreads();

  // ---- phase 2: [k|v] = xn @ Wqkv[:,128:384] ----
  float acc2[4][16];
  #pragma unroll
  for (int i = 0; i < 4; i++)
    #pragma unroll
    for (int m = 0; m < 16; m++) acc2[i][m] = 0.f;

  #pragma unroll 2
  for (int j = 0; j < 256; j++) {
    float4 a4 = *(float4*)&XT[j * 64 + (((rg << 2) + (j << 2)) & 63)];
    float av[4] = {a4.x, a4.y, a4.z, a4.w};
    const float* wrow = &Wqkv[j * 384 + 128];
    #pragma unroll
    for (int q = 0; q < 4; q++) {
      float4 w4 = *(const float4*)&wrow[(cg << 2) + (q << 6)];
      float wv[4] = {w4.x, w4.y, w4.z, w4.w};
      #pragma unroll
      for (int i = 0; i < 4; i++)
        #pragma unroll
        for (int jj = 0; jj < 4; jj++)
          acc2[i][q * 4 + jj] = fmaf(av[i], wv[jj], acc2[i][q * 4 + jj]);
    }
  }

  // ---- scores s = q_p . k ----
  float qpv[8];
  *(float4*)&qpv[0] = *(const float4*)&ws[WS_QP + (cg << 2)];
  *(float4*)&qpv[4] = *(const float4*)&ws[WS_QP + 64 + (cg << 2)];
  float sc[4];
  #pragma unroll
  for (int i = 0; i < 4; i++) {
    float s = 0.f;
    #pragma unroll
    for (int m = 0; m < 8; m++) s = fmaf(acc2[i][m], qpv[m], s);
    sc[i] = s;
  }
  #pragma unroll
  for (int m = 1; m < 16; m <<= 1) {
    #pragma unroll
    for (int i = 0; i < 4; i++) sc[i] += __shfl_xor(sc[i], m);
  }
  #pragma unroll
  for (int i = 0; i < 4; i++) {
    int gr = r0 + (rg << 2) + i;
    if (gr >= N) sc[i] = -INFINITY;
  }
  __syncthreads();   // XT reads done; reuse smem for scores/red
  if (cg == 0) {
    #pragma unroll
    for (int i = 0; i < 4; i++) scores[(rg << 2) + i] = sc[i];
  }
  __syncthreads();
  float mb = -INFINITY;
  #pragma unroll 8
  for (int r = 0; r < 64; r++) mb = fmaxf(mb, scores[r]);
  float wv4[4];
  #pragma unroll
  for (int i = 0; i < 4; i++) wv4[i] = expf(sc[i] - mb);

  // ---- weighted v accumulation: this thread's 8 v-cols over its 4 rows ----
  #pragma unroll
  for (int qq = 0; qq < 2; qq++) {
    #pragma unroll
    for (int j = 0; j < 4; j++) {
      float lv = 0.f;
      #pragma unroll
      for (int i = 0; i < 4; i++) lv = fmaf(wv4[i], acc2[i][(qq + 2) * 4 + j], lv);
      red[rg * 128 + (cg << 2) + (qq << 6) + j] = lv;
    }
  }
  __syncthreads();

  float* part = ws + WS_PART + (size_t)b * PART_STRIDE;
  if (tid < 128) {
    float s = 0.f;
    #pragma unroll
    for (int g = 0; g < 16; g++) s += red[g * 128 + tid];
    part[2 + tid] = s;
  }
  if (tid == 192) part[0] = mb;
  if (tid < 64) {
    float e = expf(scores[tid] - mb);
    #pragma unroll
    for (int m = 1; m < 64; m <<= 1) e += __shfl_xor(e, m);
    if (tid == 0) part[1] = e;
  }
}

// ---------------- K3: combine partials + 2-row FFN head + logits/softmax ----------------
__global__ __launch_bounds__(256) void k_final(
    const float* __restrict__ ws, int NB,
    const float* __restrict__ Wf1, const float* __restrict__ bf1,
    const float* __restrict__ Wf2, const float* __restrict__ bf2,
    const float* __restrict__ ln2_g, const float* __restrict__ ln2_b,
    const float* __restrict__ ln3_g, const float* __restrict__ ln3_b,
    const float* __restrict__ Wl1, const float* __restrict__ bl1,
    const float* __restrict__ Wl2, const float* __restrict__ bl2,
    float* __restrict__ out)
{
  __shared__ float wts[800];
  __shared__ float rowb[2][128];
  __shared__ float mmb[2][128];
  __shared__ float red[8];
  __shared__ float emb[256];
  __shared__ float abuf[64];
  __shared__ float lbuf[4];
  int tid = threadIdx.x, lane = tid & 63, wave = tid >> 6;
  const float* part = ws + WS_PART;
  float s0 = ws[WS_S0];

  // global max M over {s0, m_b}
  float mloc = s0;
  for (int bb = tid; bb < NB; bb += 256) mloc = fmaxf(mloc, part[(size_t)bb * 130]);
  for (int m = 1; m < 64; m <<= 1) mloc = fmaxf(mloc, __shfl_xor(mloc, m));
  if (lane == 0) red[wave] = mloc;
  __syncthreads();
  float M = fmaxf(fmaxf(red[0], red[1]), fmaxf(red[2], red[3]));

  // weights + denominator L
  float lp = 0.f;
  for (int bb = tid; bb < NB; bb += 256) {
    float w = expf(part[(size_t)bb * 130] - M);
    wts[bb] = w;
    lp = fmaf(part[(size_t)bb * 130 + 1], w, lp);
  }
  for (int m = 1; m < 64; m <<= 1) lp += __shfl_xor(lp, m);
  __syncthreads();
  if (lane == 0) red[wave] = lp;
  __syncthreads();
  float L = red[0] + red[1] + red[2] + red[3] + expf(s0 - M);

  // out_p row (0) and v0 row (1)
  if (tid < 128) {
    float e0 = expf(s0 - M);
    float v0 = ws[WS_V0 + tid];
    float a = v0 * e0;
    #pragma unroll 4
    for (int bb = 0; bb < NB; bb++) a = fmaf(part[(size_t)bb * 130 + 2 + tid], wts[bb], a);
    rowb[0][tid] = a / L;
    rowb[1][tid] = v0;
  }
  __syncthreads();

  int row = tid >> 7, k = tid & 127;
  // LN2
  float x = rowb[row][k];
  float ps = x, pq = x * x;
  for (int m = 1; m < 64; m <<= 1) { ps += __shfl_xor(ps, m); pq += __shfl_xor(pq, m); }
  __syncthreads();
  if (lane == 0) { red[wave] = ps; red[4 + wave] = pq; }
  __syncthreads();
  {
    float sum = red[row * 2] + red[row * 2 + 1];
    float sq  = red[4 + row * 2] + red[4 + row * 2 + 1];
    float mu = sum * (1.f / 128.f);
    float var = sq * (1.f / 128.f) - mu * mu;
    x = (x - mu) * rsqrtf(var + LN_EPS) * ln2_g[k] + ln2_b[k];
  }
  mmb[row][k] = x;
  __syncthreads();
  float t1 = bf1[k];
  for (int j = 0; j < 128; j++) t1 = fmaf(mmb[row][j], Wf1[j * 128 + k], t1);
  float gg = t1 * 0.5f * (1.f + erff(t1 * 0.70710678118654752f)); // exact GELU
  __syncthreads();
  rowb[row][k] = gg;
  __syncthreads();
  float t2 = bf2[k];
  for (int j = 0; j < 128; j++) t2 = fmaf(rowb[row][j], Wf2[j * 128 + k], t2);
  // LN3
  ps = t2; pq = t2 * t2;
  for (int m = 1; m < 64; m <<= 1) { ps += __shfl_xor(ps, m); pq += __shfl_xor(pq, m); }
  __syncthreads();
  if (lane == 0) { red[wave] = ps; red[4 + wave] = pq; }
  __syncthreads();
  {
    float sum = red[row * 2] + red[row * 2 + 1];
    float sq  = red[4 + row * 2] + red[4 + row * 2 + 1];
    float mu = sum * (1.f / 128.f);
    float var = sq * (1.f / 128.f) - mu * mu;
    t2 = (t2 - mu) * rsqrtf(var + LN_EPS) * ln3_g[k] + ln3_b[k];
  }
  emb[row * 128 + k] = t2;
  __syncthreads();
  if (tid < 64) {
    float a = bl1[tid];
    for (int j = 0; j < 256; j++) a = fmaf(emb[j], Wl1[j * 64 + tid], a);
    abuf[tid] = fmaxf(a, 0.f);
  }
  __syncthreads();
  if (tid < 4) {
    float lg = bl2[tid];
    for (int j = 0; j < 64; j++) lg = fmaf(abuf[j], Wl2[j * 4 + tid], lg);
    lbuf[tid] = lg;
  }
  __syncthreads();
  if (tid < 4) {
    float m4 = fmaxf(fmaxf(lbuf[0], lbuf[1]), fmaxf(lbuf[2], lbuf[3]));
    float e0 = expf(lbuf[0] - m4), e1 = expf(lbuf[1] - m4);
    float e2 = expf(lbuf[2] - m4), e3 = expf(lbuf[3] - m4);
    float ssum = e0 + e1 + e2 + e3;
    out[tid] = lbuf[tid];
    out[4 + tid] = expf(lbuf[tid] - m4) / ssum;
  }
}

extern "C" void kernel_launch(void* const* d_in, const int* in_sizes, int n_in,
                              void* d_out, int out_size, void* d_ws, size_t ws_size,
                              hipStream_t stream) {
  const float* wsi    = (const float*)d_in[0];
  const float* x_omic = (const float*)d_in[1];
  const float* W1     = (const float*)d_in[2];
  const float* b1     = (const float*)d_in[3];
  const float* W2     = (const float*)d_in[4];
  const float* b2     = (const float*)d_in[5];
  const float* Wp     = (const float*)d_in[6];
  const float* bp     = (const float*)d_in[7];
  const float* ln1_g  = (const float*)d_in[8];
  const float* ln1_b  = (const float*)d_in[9];
  const float* Wqkv   = (const float*)d_in[10];
  const float* ln2_g  = (const float*)d_in[11];
  const float* ln2_b  = (const float*)d_in[12];
  const float* Wf1    = (const float*)d_in[13];
  const float* bf1    = (const float*)d_in[14];
  const float* Wf2    = (const float*)d_in[15];
  const float* bf2    = (const float*)d_in[16];
  const float* ln3_g  = (const float*)d_in[17];
  const float* ln3_b  = (const float*)d_in[18];
  const float* Wl1    = (const float*)d_in[19];
  const float* bl1    = (const float*)d_in[20];
  const float* Wl2    = (const float*)d_in[21];
  const float* bl2    = (const float*)d_in[22];
  float* ws   = (float*)d_ws;
  float* outp = (float*)d_out;

  int N = in_sizes[0] / 1024;
  int d_omic = in_sizes[1];
  int NB = (N + 63) / 64;

  k_h1<<<16, 256, 0, stream>>>(x_omic, W1, d_omic, ws);
  k_omic<<<1, 256, 0, stream>>>(b1, W2, b2, Wqkv, ln1_g, ln1_b, ws);
  k_main<<<NB, 256, 0, stream>>>(wsi, N, Wp, bp, ln1_g, ln1_b, Wqkv, ws);
  k_final<<<1, 256, 0, stream>>>(ws, NB, Wf1, bf1, Wf2, bf2, ln2_g, ln2_b,
                                 ln3_g, ln3_b, Wl1, bl1, Wl2, bl2, outp);
}

// Round 2
// 241.006 us; speedup vs baseline: 2.6085x; 2.6085x over previous
//
#include <hip/hip_runtime.h>
#include <math.h>

#define LN_EPS 1e-5f

typedef unsigned short ushortT;
typedef short bf16x8 __attribute__((ext_vector_type(8)));
typedef float f32x4 __attribute__((ext_vector_type(4)));

// ws layout (float offsets)
#define WS_QP   0            // q_p * scale (128)
#define WS_V0   128          // v0 (128)
#define WS_S0   256          // s0 scalar
#define WS_H1P  512          // 16*256 h1 partials
#define WS_PART 4608         // per-block partials: [acc 128][m][l][pad] stride 132
#define PART_STRIDE 132
#define PART_M 128
#define PART_L 129
#define WS_WPT  131072       // ushort region: WpT[256][1024] bf16 (512KB)
#define WS_WKVT 262144       // ushort region: WkvT[256][256] bf16 (128KB)

__device__ __forceinline__ float elu1(float x){ return x > 0.f ? x : expm1f(x); }
__device__ __forceinline__ unsigned short f2bf(float x){
  unsigned u = __float_as_uint(x);
  return (unsigned short)((u + 0x7fffu + ((u >> 16) & 1u)) >> 16);
}

// ---------------- K_prep: transpose+convert Wp and Wqkv(k|v) to bf16 ----------------
__global__ __launch_bounds__(256) void k_prep(const float* __restrict__ Wp,
    const float* __restrict__ Wqkv, ushortT* __restrict__ wpt, ushortT* __restrict__ wkvt)
{
  int n = blockIdx.x, t = threadIdx.x;
  if (n < 256) {
    // WpT[n][k] = Wp[k][n]
    for (int k = t; k < 1024; k += 256) wpt[n * 1024 + k] = f2bf(Wp[(size_t)k * 256 + n]);
  } else {
    int m = n - 256;
    // WkvT[m][k] = Wqkv[k][128+m]  (m<128 -> k-proj, m>=128 -> v-proj)
    for (int k = t; k < 256; k += 256) wkvt[m * 256 + k] = f2bf(Wqkv[(size_t)k * 384 + 128 + m]);
  }
}

// ---------------- K0: h1 partial dots ----------------
__global__ __launch_bounds__(256) void k_h1(const float* __restrict__ x,
    const float* __restrict__ W1, int d_omic, float* __restrict__ ws)
{
  int g = blockIdx.x, tid = threadIdx.x;
  int i0 = g * 99, i1 = min(i0 + 99, d_omic);
  __shared__ float xs[112];
  for (int i = i0 + tid; i < i1; i += 256) xs[i - i0] = x[i];
  __syncthreads();
  float s = 0.f;
  for (int i = i0; i < i1; i++) s = fmaf(xs[i - i0], W1[(size_t)i * 256 + tid], s);
  ws[WS_H1P + g * 256 + tid] = s;
}

// ---------------- K1: omic MLP + token0 LN1 + q_p/k_p/v0 + s0 (exact fp32) ----------------
__global__ __launch_bounds__(256) void k_omic(
    const float* __restrict__ b1,
    const float* __restrict__ W2, const float* __restrict__ b2,
    const float* __restrict__ Wqkv,
    const float* __restrict__ ln1_g, const float* __restrict__ ln1_b,
    float* __restrict__ ws)
{
  __shared__ float h1[256];
  __shared__ float xn0[256];
  __shared__ float qs[128], ks[128];
  __shared__ float red[8];
  int tid = threadIdx.x, lane = tid & 63, wave = tid >> 6;

  float s = b1[tid];
  for (int g = 0; g < 16; g++) s += ws[WS_H1P + g * 256 + tid];
  h1[tid] = elu1(s);
  __syncthreads();

  s = b2[tid];
  for (int i = 0; i < 256; i++) s = fmaf(h1[i], W2[i * 256 + tid], s);
  float t0 = elu1(s);

  float ps = t0, pq = t0 * t0;
  for (int m = 1; m < 64; m <<= 1) { ps += __shfl_xor(ps, m); pq += __shfl_xor(pq, m); }
  if (lane == 0) { red[wave] = ps; red[4 + wave] = pq; }
  __syncthreads();
  float mu = (red[0] + red[1] + red[2] + red[3]) * (1.f / 256.f);
  float var = (red[4] + red[5] + red[6] + red[7]) * (1.f / 256.f) - mu * mu;
  float xn = (t0 - mu) * rsqrtf(var + LN_EPS) * ln1_g[tid] + ln1_b[tid];
  xn0[tid] = xn;
  __syncthreads();

  float a = 0.f;
  for (int j = 0; j < 256; j++) a = fmaf(xn0[j], Wqkv[j * 384 + tid], a);
  if (tid < 128) { float q = a * 0.088388347648318447f; qs[tid] = q; ws[WS_QP + tid] = q; }
  else           { ks[tid - 128] = a; }
  if (tid < 128) {
    float av = 0.f;
    for (int j = 0; j < 256; j++) av = fmaf(xn0[j], Wqkv[j * 384 + 256 + tid], av);
    ws[WS_V0 + tid] = av;
  }
  __syncthreads();
  float p = (tid < 128) ? qs[tid] * ks[tid] : 0.f;
  for (int m = 1; m < 64; m <<= 1) p += __shfl_xor(p, m);
  if (lane == 0) red[wave] = p;
  __syncthreads();
  if (tid == 0) ws[WS_S0] = red[0] + red[1] + red[2] + red[3];
}

// ---------------- K2: MFMA fused wsi@Wp -> LN1 -> [k|v] -> scores -> partials ----------------
// Orientation: D1[m=Wp-outcol][n=wsi-row] = WpT(A) x wsiT(B).
//   a-frag: lane holds A[m=l&15][k=8*(l>>4)+e] (contiguous k, 16B load)
//   b-frag: lane holds B[k=8*(l>>4)+e][n=l&15] = wsi[row=n][k..k+7]
//   C/D:    lane holds D[m=4*(l>>4)+r][n=l&15]   (m89-verified layout)
__global__ __launch_bounds__(256, 3) void k_main(
    const float* __restrict__ wsi, int N,
    const ushortT* __restrict__ wpt, const ushortT* __restrict__ wkvt,
    const float* __restrict__ bp,
    const float* __restrict__ ln1_g, const float* __restrict__ ln1_b,
    float* __restrict__ ws)
{
  __shared__ __align__(16) ushortT As[64 * 64];    // wsi tile [row][k], XOR-swizzled, 8KB
  __shared__ __align__(16) ushortT Xn[64 * 256];   // xn [row][col], XOR-swizzled, 32KB
  __shared__ __align__(16) float   red[4 * 64 * 2];// LN partials / score partials
  __shared__ float wtsL[64];

  const int tid = threadIdx.x;
  const int lane = tid & 63, wv = tid >> 6;
  const int l15 = lane & 15, lh = lane >> 4;
  const int b = blockIdx.x, r0 = b * 64;

  // staging map: thread -> (row, k-quad)
  const int rs = tid & 63, kq = tid >> 6;
  const size_t wsiRow = (size_t)(r0 + rs) * 1024;
  const bool rsValid = (r0 + rs) < N;
  const unsigned swzS = (unsigned)((rs & 7) << 4);

  int aBase[4];
  #pragma unroll
  for (int mt = 0; mt < 4; ++mt)
    aBase[mt] = (64 * wv + 16 * mt + l15) * 1024 + 8 * lh;

  const f32x4 z4 = {0.f, 0.f, 0.f, 0.f};
  f32x4 acc[4][4];
  #pragma unroll
  for (int mt = 0; mt < 4; ++mt)
    #pragma unroll
    for (int nt = 0; nt < 4; ++nt) acc[mt][nt] = z4;

  float4 pf[4];
  auto stage_load = [&](int s) {
    #pragma unroll
    for (int u = 0; u < 4; ++u) {
      if (rsValid) pf[u] = *(const float4*)&wsi[wsiRow + s * 64 + kq * 16 + u * 4];
      else pf[u] = make_float4(0.f, 0.f, 0.f, 0.f);
    }
  };
  auto stage_write = [&]() {
    #pragma unroll
    for (int u = 0; u < 4; ++u) {
      unsigned p0 = (unsigned)f2bf(pf[u].x) | ((unsigned)f2bf(pf[u].y) << 16);
      unsigned p1 = (unsigned)f2bf(pf[u].z) | ((unsigned)f2bf(pf[u].w) << 16);
      unsigned off = (unsigned)(rs * 128 + kq * 32 + u * 8) ^ swzS;
      *(uint2*)((char*)As + off) = make_uint2(p0, p1);
    }
  };

  // ---- phase 1: T = wsi @ Wp via MFMA, K=1024 in 16 steps of 64 ----
  stage_load(0);
  stage_write();
  __syncthreads();
  for (int s = 0; s < 16; ++s) {
    if (s < 15) stage_load(s + 1);               // T14: issue next-tile loads early
    #pragma unroll
    for (int kc = 0; kc < 2; ++kc) {
      bf16x8 af[4], bfr[4];
      #pragma unroll
      for (int mt = 0; mt < 4; ++mt)
        af[mt] = *(const bf16x8*)(wpt + (aBase[mt] + 64 * s + 32 * kc));
      #pragma unroll
      for (int nt = 0; nt < 4; ++nt) {
        int row = l15 + 16 * nt;
        unsigned off = (unsigned)(row * 128 + lh * 16 + kc * 64) ^ (unsigned)((row & 7) << 4);
        bfr[nt] = *(const bf16x8*)((const char*)As + off);
      }
      #pragma unroll
      for (int mt = 0; mt < 4; ++mt)
        #pragma unroll
        for (int nt = 0; nt < 4; ++nt)
          acc[mt][nt] = __builtin_amdgcn_mfma_f32_16x16x32_bf16(af[mt], bfr[nt], acc[mt][nt], 0, 0, 0);
    }
    __syncthreads();
    if (s < 15) { stage_write(); __syncthreads(); }
  }

  // ---- bias + LN1 ----
  float4 bp4[4], g4[4], b4[4];
  #pragma unroll
  for (int mt = 0; mt < 4; ++mt) {
    int m0 = 64 * wv + 16 * mt + 4 * lh;
    bp4[mt] = *(const float4*)&bp[m0];
    g4[mt]  = *(const float4*)&ln1_g[m0];
    b4[mt]  = *(const float4*)&ln1_b[m0];
  }
  float ps[4], pq[4];
  #pragma unroll
  for (int nt = 0; nt < 4; ++nt) { ps[nt] = 0.f; pq[nt] = 0.f; }
  #pragma unroll
  for (int mt = 0; mt < 4; ++mt) {
    const float bb4[4] = {bp4[mt].x, bp4[mt].y, bp4[mt].z, bp4[mt].w};
    #pragma unroll
    for (int nt = 0; nt < 4; ++nt)
      #pragma unroll
      for (int r = 0; r < 4; ++r) {
        float v = acc[mt][nt][r] + bb4[r];
        acc[mt][nt][r] = v;
        ps[nt] += v; pq[nt] += v * v;
      }
  }
  #pragma unroll
  for (int nt = 0; nt < 4; ++nt) {
    ps[nt] += __shfl_xor(ps[nt], 16); pq[nt] += __shfl_xor(pq[nt], 16);
    ps[nt] += __shfl_xor(ps[nt], 32); pq[nt] += __shfl_xor(pq[nt], 32);
  }
  if (lh == 0) {
    #pragma unroll
    for (int nt = 0; nt < 4; ++nt) {
      int row = l15 + 16 * nt;
      red[(wv * 64 + row) * 2]     = ps[nt];
      red[(wv * 64 + row) * 2 + 1] = pq[nt];
    }
  }
  __syncthreads();
  float mu[4], rstd[4];
  #pragma unroll
  for (int nt = 0; nt < 4; ++nt) {
    int row = l15 + 16 * nt;
    float s_ = 0.f, q_ = 0.f;
    #pragma unroll
    for (int w2 = 0; w2 < 4; ++w2) { s_ += red[(w2 * 64 + row) * 2]; q_ += red[(w2 * 64 + row) * 2 + 1]; }
    float m_ = s_ * (1.f / 256.f);
    float v_ = q_ * (1.f / 256.f) - m_ * m_;
    mu[nt] = m_; rstd[nt] = rsqrtf(v_ + LN_EPS);
  }
  // write xn (bf16, swizzled [row][col])
  #pragma unroll
  for (int nt = 0; nt < 4; ++nt) {
    int row = l15 + 16 * nt;
    unsigned rswz = (unsigned)((row & 7) << 4);
    #pragma unroll
    for (int mt = 0; mt < 4; ++mt) {
      float x0 = (acc[mt][nt][0] - mu[nt]) * rstd[nt] * g4[mt].x + b4[mt].x;
      float x1 = (acc[mt][nt][1] - mu[nt]) * rstd[nt] * g4[mt].y + b4[mt].y;
      float x2 = (acc[mt][nt][2] - mu[nt]) * rstd[nt] * g4[mt].z + b4[mt].z;
      float x3 = (acc[mt][nt][3] - mu[nt]) * rstd[nt] * g4[mt].w + b4[mt].w;
      unsigned p0 = (unsigned)f2bf(x0) | ((unsigned)f2bf(x1) << 16);
      unsigned p1 = (unsigned)f2bf(x2) | ((unsigned)f2bf(x3) << 16);
      int m0 = 64 * wv + 16 * mt + 4 * lh;
      unsigned off = (unsigned)(row * 512 + m0 * 2) ^ rswz;
      *(uint2*)((char*)Xn + off) = make_uint2(p0, p1);
    }
  }
  __syncthreads();

  // ---- phase 2: D2[m=kv-col][n=row] = WkvT(A) x xnT(B), K=256 ----
  f32x4 acc2[4][4];
  #pragma unroll
  for (int mt = 0; mt < 4; ++mt)
    #pragma unroll
    for (int nt = 0; nt < 4; ++nt) acc2[mt][nt] = z4;
  int a2Base[4];
  #pragma unroll
  for (int mt = 0; mt < 4; ++mt)
    a2Base[mt] = (64 * wv + 16 * mt + l15) * 256 + 8 * lh;

  #pragma unroll 2
  for (int kk = 0; kk < 8; ++kk) {
    bf16x8 af[4], bfr[4];
    #pragma unroll
    for (int mt = 0; mt < 4; ++mt)
      af[mt] = *(const bf16x8*)(wkvt + (a2Base[mt] + 32 * kk));
    #pragma unroll
    for (int nt = 0; nt < 4; ++nt) {
      int row = l15 + 16 * nt;
      unsigned off = (unsigned)(row * 512 + lh * 16 + kk * 64) ^ (unsigned)((row & 7) << 4);
      bfr[nt] = *(const bf16x8*)((const char*)Xn + off);
    }
    #pragma unroll
    for (int mt = 0; mt < 4; ++mt)
      #pragma unroll
      for (int nt = 0; nt < 4; ++nt)
        acc2[mt][nt] = __builtin_amdgcn_mfma_f32_16x16x32_bf16(af[mt], bfr[nt], acc2[mt][nt], 0, 0, 0);
  }

  float* part = ws + WS_PART + (size_t)b * PART_STRIDE;

  // ---- scores (waves 0,1 hold k-proj) ----
  if (wv < 2) {
    float4 qp4[4];
    #pragma unroll
    for (int mt = 0; mt < 4; ++mt)
      qp4[mt] = *(const float4*)&ws[WS_QP + 64 * wv + 16 * mt + 4 * lh];
    float sp[4];
    #pragma unroll
    for (int nt = 0; nt < 4; ++nt) {
      float s_ = 0.f;
      #pragma unroll
      for (int mt = 0; mt < 4; ++mt) {
        s_ = fmaf(qp4[mt].x, acc2[mt][nt][0], s_);
        s_ = fmaf(qp4[mt].y, acc2[mt][nt][1], s_);
        s_ = fmaf(qp4[mt].z, acc2[mt][nt][2], s_);
        s_ = fmaf(qp4[mt].w, acc2[mt][nt][3], s_);
      }
      sp[nt] = s_;
    }
    #pragma unroll
    for (int nt = 0; nt < 4; ++nt) {
      sp[nt] += __shfl_xor(sp[nt], 16);
      sp[nt] += __shfl_xor(sp[nt], 32);
    }
    if (lh == 0) {
      #pragma unroll
      for (int nt = 0; nt < 4; ++nt) red[wv * 64 + 16 * nt + l15] = sp[nt];
    }
  }
  __syncthreads();
  if (tid < 64) {
    int gr = r0 + tid;
    float s_ = red[tid] + red[64 + tid];
    if (gr >= N) s_ = -INFINITY;
    float mb = s_;
    #pragma unroll
    for (int m = 1; m < 64; m <<= 1) mb = fmaxf(mb, __shfl_xor(mb, m));
    float e = (gr < N) ? expf(s_ - mb) : 0.f;
    float l_ = e;
    #pragma unroll
    for (int m = 1; m < 64; m <<= 1) l_ += __shfl_xor(l_, m);
    wtsL[tid] = e;
    if (tid == 0) { part[PART_M] = mb; part[PART_L] = l_; }
  }
  __syncthreads();
  // ---- weighted-V partials (waves 2,3 hold v-proj) ----
  if (wv >= 2) {
    int wv2 = wv - 2;
    float wr[4];
    #pragma unroll
    for (int nt = 0; nt < 4; ++nt) wr[nt] = wtsL[16 * nt + l15];
    #pragma unroll
    for (int mt = 0; mt < 4; ++mt) {
      float vs0 = 0.f, vs1 = 0.f, vs2 = 0.f, vs3 = 0.f;
      #pragma unroll
      for (int nt = 0; nt < 4; ++nt) {
        vs0 = fmaf(wr[nt], acc2[mt][nt][0], vs0);
        vs1 = fmaf(wr[nt], acc2[mt][nt][1], vs1);
        vs2 = fmaf(wr[nt], acc2[mt][nt][2], vs2);
        vs3 = fmaf(wr[nt], acc2[mt][nt][3], vs3);
      }
      #pragma unroll
      for (int m = 1; m < 16; m <<= 1) {
        vs0 += __shfl_xor(vs0, m); vs1 += __shfl_xor(vs1, m);
        vs2 += __shfl_xor(vs2, m); vs3 += __shfl_xor(vs3, m);
      }
      if (l15 == 0)
        *(float4*)&part[64 * wv2 + 16 * mt + 4 * lh] = make_float4(vs0, vs1, vs2, vs3);
    }
  }
}

// ---------------- K3: combine partials + 2-row FFN head + logits/softmax ----------------
__global__ __launch_bounds__(256) void k_final(
    const float* __restrict__ ws, int NB,
    const float* __restrict__ Wf1, const float* __restrict__ bf1,
    const float* __restrict__ Wf2, const float* __restrict__ bf2,
    const float* __restrict__ ln2_g, const float* __restrict__ ln2_b,
    const float* __restrict__ ln3_g, const float* __restrict__ ln3_b,
    const float* __restrict__ Wl1, const float* __restrict__ bl1,
    const float* __restrict__ Wl2, const float* __restrict__ bl2,
    float* __restrict__ out)
{
  __shared__ float wts[800];
  __shared__ float rowb[2][128];
  __shared__ float mmb[2][128];
  __shared__ float red[8];
  __shared__ float emb[256];
  __shared__ float abuf[64];
  __shared__ float lbuf[4];
  int tid = threadIdx.x, lane = tid & 63, wave = tid >> 6;
  const float* part = ws + WS_PART;
  float s0 = ws[WS_S0];

  float mloc = s0;
  for (int bb = tid; bb < NB; bb += 256) mloc = fmaxf(mloc, part[(size_t)bb * PART_STRIDE + PART_M]);
  for (int m = 1; m < 64; m <<= 1) mloc = fmaxf(mloc, __shfl_xor(mloc, m));
  if (lane == 0) red[wave] = mloc;
  __syncthreads();
  float M = fmaxf(fmaxf(red[0], red[1]), fmaxf(red[2], red[3]));

  float lp = 0.f;
  for (int bb = tid; bb < NB; bb += 256) {
    float w = expf(part[(size_t)bb * PART_STRIDE + PART_M] - M);
    wts[bb] = w;
    lp = fmaf(part[(size_t)bb * PART_STRIDE + PART_L], w, lp);
  }
  for (int m = 1; m < 64; m <<= 1) lp += __shfl_xor(lp, m);
  __syncthreads();
  if (lane == 0) red[wave] = lp;
  __syncthreads();
  float L = red[0] + red[1] + red[2] + red[3] + expf(s0 - M);

  if (tid < 128) {
    float e0 = expf(s0 - M);
    float v0 = ws[WS_V0 + tid];
    float a = v0 * e0;
    #pragma unroll 4
    for (int bb = 0; bb < NB; bb++) a = fmaf(part[(size_t)bb * PART_STRIDE + tid], wts[bb], a);
    rowb[0][tid] = a / L;
    rowb[1][tid] = v0;
  }
  __syncthreads();

  int row = tid >> 7, k = tid & 127;
  float x = rowb[row][k];
  float ps = x, pq = x * x;
  for (int m = 1; m < 64; m <<= 1) { ps += __shfl_xor(ps, m); pq += __shfl_xor(pq, m); }
  __syncthreads();
  if (lane == 0) { red[wave] = ps; red[4 + wave] = pq; }
  __syncthreads();
  {
    float sum = red[row * 2] + red[row * 2 + 1];
    float sq  = red[4 + row * 2] + red[4 + row * 2 + 1];
    float mu = sum * (1.f / 128.f);
    float var = sq * (1.f / 128.f) - mu * mu;
    x = (x - mu) * rsqrtf(var + LN_EPS) * ln2_g[k] + ln2_b[k];
  }
  mmb[row][k] = x;
  __syncthreads();
  float t1 = bf1[k];
  for (int j = 0; j < 128; j++) t1 = fmaf(mmb[row][j], Wf1[j * 128 + k], t1);
  float gg = t1 * 0.5f * (1.f + erff(t1 * 0.70710678118654752f));
  __syncthreads();
  rowb[row][k] = gg;
  __syncthreads();
  float t2 = bf2[k];
  for (int j = 0; j < 128; j++) t2 = fmaf(rowb[row][j], Wf2[j * 128 + k], t2);
  ps = t2; pq = t2 * t2;
  for (int m = 1; m < 64; m <<= 1) { ps += __shfl_xor(ps, m); pq += __shfl_xor(pq, m); }
  __syncthreads();
  if (lane == 0) { red[wave] = ps; red[4 + wave] = pq; }
  __syncthreads();
  {
    float sum = red[row * 2] + red[row * 2 + 1];
    float sq  = red[4 + row * 2] + red[4 + row * 2 + 1];
    float mu = sum * (1.f / 128.f);
    float var = sq * (1.f / 128.f) - mu * mu;
    t2 = (t2 - mu) * rsqrtf(var + LN_EPS) * ln3_g[k] + ln3_b[k];
  }
  emb[row * 128 + k] = t2;
  __syncthreads();
  if (tid < 64) {
    float a = bl1[tid];
    for (int j = 0; j < 256; j++) a = fmaf(emb[j], Wl1[j * 64 + tid], a);
    abuf[tid] = fmaxf(a, 0.f);
  }
  __syncthreads();
  if (tid < 4) {
    float lg = bl2[tid];
    for (int j = 0; j < 64; j++) lg = fmaf(abuf[j], Wl2[j * 4 + tid], lg);
    lbuf[tid] = lg;
  }
  __syncthreads();
  if (tid < 4) {
    float m4 = fmaxf(fmaxf(lbuf[0], lbuf[1]), fmaxf(lbuf[2], lbuf[3]));
    float e0 = expf(lbuf[0] - m4), e1 = expf(lbuf[1] - m4);
    float e2 = expf(lbuf[2] - m4), e3 = expf(lbuf[3] - m4);
    float ssum = e0 + e1 + e2 + e3;
    out[tid] = lbuf[tid];
    out[4 + tid] = expf(lbuf[tid] - m4) / ssum;
  }
}

extern "C" void kernel_launch(void* const* d_in, const int* in_sizes, int n_in,
                              void* d_out, int out_size, void* d_ws, size_t ws_size,
                              hipStream_t stream) {
  const float* wsi    = (const float*)d_in[0];
  const float* x_omic = (const float*)d_in[1];
  const float* W1     = (const float*)d_in[2];
  const float* b1     = (const float*)d_in[3];
  const float* W2     = (const float*)d_in[4];
  const float* b2     = (const float*)d_in[5];
  const float* Wp     = (const float*)d_in[6];
  const float* bp     = (const float*)d_in[7];
  const float* ln1_g  = (const float*)d_in[8];
  const float* ln1_b  = (const float*)d_in[9];
  const float* Wqkv   = (const float*)d_in[10];
  const float* ln2_g  = (const float*)d_in[11];
  const float* ln2_b  = (const float*)d_in[12];
  const float* Wf1    = (const float*)d_in[13];
  const float* bf1    = (const float*)d_in[14];
  const float* Wf2    = (const float*)d_in[15];
  const float* bf2    = (const float*)d_in[16];
  const float* ln3_g  = (const float*)d_in[17];
  const float* ln3_b  = (const float*)d_in[18];
  const float* Wl1    = (const float*)d_in[19];
  const float* bl1    = (const float*)d_in[20];
  const float* Wl2    = (const float*)d_in[21];
  const float* bl2    = (const float*)d_in[22];
  float* ws   = (float*)d_ws;
  float* outp = (float*)d_out;
  ushortT* wpt  = (ushortT*)(ws + WS_WPT);
  ushortT* wkvt = (ushortT*)(ws + WS_WKVT);

  int N = in_sizes[0] / 1024;
  int d_omic = in_sizes[1];
  int NB = (N + 63) / 64;

  k_prep<<<512, 256, 0, stream>>>(Wp, Wqkv, wpt, wkvt);
  k_h1<<<16, 256, 0, stream>>>(x_omic, W1, d_omic, ws);
  k_omic<<<1, 256, 0, stream>>>(b1, W2, b2, Wqkv, ln1_g, ln1_b, ws);
  k_main<<<NB, 256, 0, stream>>>(wsi, N, wpt, wkvt, bp, ln1_g, ln1_b, ws);
  k_final<<<1, 256, 0, stream>>>(ws, NB, Wf1, bf1, Wf2, bf2, ln2_g, ln2_b,
                                 ln3_g, ln3_b, Wl1, bl1, Wl2, bl2, outp);
}

// Round 3
// 187.818 us; speedup vs baseline: 3.3472x; 1.2832x over previous
//
#include <hip/hip_runtime.h>
#include <hip/hip_bf16.h>
#include <math.h>

#define LN_EPS 1e-5f

typedef unsigned short ushortT;
typedef short bf16x8 __attribute__((ext_vector_type(8)));
typedef float f32x4 __attribute__((ext_vector_type(4)));

// ws layout (float offsets)
#define WS_QP   0            // q_p * scale (128)
#define WS_V0   128          // v0 (128)
#define WS_S0   256          // s0 scalar
#define WS_LL   258          // softmax denominator L
#define WS_E0   259          // exp(s0 - M)
#define WS_H1P  512          // 16*256 h1 partials
#define WS_PART 4608         // per-block partials: [acc 128][m][l][pad] stride 132
#define PART_STRIDE 132
#define PART_M 128
#define PART_L 129
#define WS_WTS  108000       // per-block softmax weights (NB floats)
#define WS_GP   109000       // 32 x 128 combiner partial sums
#define NCOMB   32
#define WS_WPT  131072       // ushort region: WpT[256][1024] bf16 (512KB)
#define WS_WKVT 262144       // ushort region: WkvT[256][256] bf16 (128KB)

__device__ __forceinline__ float elu1(float x){ return x > 0.f ? x : expm1f(x); }
__device__ __forceinline__ unsigned short f2bf(float x){
  unsigned u = __float_as_uint(x);
  return (unsigned short)((u + 0x7fffu + ((u >> 16) & 1u)) >> 16);
}
__device__ __forceinline__ unsigned pk2(float lo, float hi){
  union { __hip_bfloat162 h; unsigned u; } cv;
  cv.h = __float22bfloat162_rn(make_float2(lo, hi));
  return cv.u;
}

// ---------------- K_prep: transpose+convert Wp and Wqkv(k|v) to bf16 ----------------
__global__ __launch_bounds__(256) void k_prep(const float* __restrict__ Wp,
    const float* __restrict__ Wqkv, ushortT* __restrict__ wpt, ushortT* __restrict__ wkvt)
{
  int n = blockIdx.x, t = threadIdx.x;
  if (n < 256) {
    for (int k = t; k < 1024; k += 256) wpt[n * 1024 + k] = f2bf(Wp[(size_t)k * 256 + n]);
  } else {
    int m = n - 256;
    for (int k = t; k < 256; k += 256) wkvt[m * 256 + k] = f2bf(Wqkv[(size_t)k * 384 + 128 + m]);
  }
}

// ---------------- K0: h1 partial dots ----------------
__global__ __launch_bounds__(256) void k_h1(const float* __restrict__ x,
    const float* __restrict__ W1, int d_omic, float* __restrict__ ws)
{
  int g = blockIdx.x, tid = threadIdx.x;
  int i0 = g * 99, i1 = min(i0 + 99, d_omic);
  __shared__ float xs[112];
  for (int i = i0 + tid; i < i1; i += 256) xs[i - i0] = x[i];
  __syncthreads();
  float s = 0.f;
  for (int i = i0; i < i1; i++) s = fmaf(xs[i - i0], W1[(size_t)i * 256 + tid], s);
  ws[WS_H1P + g * 256 + tid] = s;
}

// ---------------- K1: omic MLP + token0 LN1 + q_p/k_p/v0 + s0 (exact fp32) ----------------
__global__ __launch_bounds__(256) void k_omic(
    const float* __restrict__ b1,
    const float* __restrict__ W2, const float* __restrict__ b2,
    const float* __restrict__ Wqkv,
    const float* __restrict__ ln1_g, const float* __restrict__ ln1_b,
    float* __restrict__ ws)
{
  __shared__ float h1[256];
  __shared__ float xn0[256];
  __shared__ float qs[128], ks[128];
  __shared__ float red[8];
  int tid = threadIdx.x, lane = tid & 63, wave = tid >> 6;

  float s = b1[tid];
  for (int g = 0; g < 16; g++) s += ws[WS_H1P + g * 256 + tid];
  h1[tid] = elu1(s);
  __syncthreads();

  s = b2[tid];
  for (int i = 0; i < 256; i++) s = fmaf(h1[i], W2[i * 256 + tid], s);
  float t0 = elu1(s);

  float ps = t0, pq = t0 * t0;
  for (int m = 1; m < 64; m <<= 1) { ps += __shfl_xor(ps, m); pq += __shfl_xor(pq, m); }
  if (lane == 0) { red[wave] = ps; red[4 + wave] = pq; }
  __syncthreads();
  float mu = (red[0] + red[1] + red[2] + red[3]) * (1.f / 256.f);
  float var = (red[4] + red[5] + red[6] + red[7]) * (1.f / 256.f) - mu * mu;
  float xn = (t0 - mu) * rsqrtf(var + LN_EPS) * ln1_g[tid] + ln1_b[tid];
  xn0[tid] = xn;
  __syncthreads();

  float a = 0.f;
  for (int j = 0; j < 256; j++) a = fmaf(xn0[j], Wqkv[j * 384 + tid], a);
  if (tid < 128) { float q = a * 0.088388347648318447f; qs[tid] = q; ws[WS_QP + tid] = q; }
  else           { ks[tid - 128] = a; }
  if (tid < 128) {
    float av = 0.f;
    for (int j = 0; j < 256; j++) av = fmaf(xn0[j], Wqkv[j * 384 + 256 + tid], av);
    ws[WS_V0 + tid] = av;
  }
  __syncthreads();
  float p = (tid < 128) ? qs[tid] * ks[tid] : 0.f;
  for (int m = 1; m < 64; m <<= 1) p += __shfl_xor(p, m);
  if (lane == 0) red[wave] = p;
  __syncthreads();
  if (tid == 0) ws[WS_S0] = red[0] + red[1] + red[2] + red[3];
}

// ---------------- K2: MFMA fused wsi@Wp -> LN1 -> [k|v] -> scores -> partials ----------------
// D1[m=Wp-outcol][n=wsi-row] = WpT(A) x wsiT(B); C/D lane layout m89-verified.
__global__ __launch_bounds__(256, 3) void k_main(
    const float* __restrict__ wsi, int N,
    const ushortT* __restrict__ wpt, const ushortT* __restrict__ wkvt,
    const float* __restrict__ bp,
    const float* __restrict__ ln1_g, const float* __restrict__ ln1_b,
    float* __restrict__ ws)
{
  __shared__ __align__(16) ushortT As[2][64 * 64]; // wsi tile dbuf [row][k] swizzled, 2x8KB
  __shared__ __align__(16) ushortT Xn[64 * 256];   // xn [row][col] swizzled, 32KB
  __shared__ __align__(16) float   red[4 * 64 * 2];
  __shared__ float wtsL[64];

  const int tid = threadIdx.x;
  const int lane = tid & 63, wv = tid >> 6;
  const int l15 = lane & 15, lh = lane >> 4;
  const int b = blockIdx.x, r0 = b * 64;

  // coalesced staging map: thread -> (row, 16-float chunk)
  const int sr = tid >> 2, sc = tid & 3;
  const size_t wsiRow = (size_t)(r0 + sr) * 1024;
  const bool srValid = (r0 + sr) < N;
  const unsigned sraw = (unsigned)(sr * 128 + sc * 32);
  const unsigned sswz = (unsigned)((sr & 7) << 4);

  int aBase[4];
  #pragma unroll
  for (int mt = 0; mt < 4; ++mt)
    aBase[mt] = (64 * wv + 16 * mt + l15) * 1024 + 8 * lh;

  const f32x4 z4 = {0.f, 0.f, 0.f, 0.f};
  f32x4 acc[4][4];
  #pragma unroll
  for (int mt = 0; mt < 4; ++mt)
    #pragma unroll
    for (int nt = 0; nt < 4; ++nt) acc[mt][nt] = z4;

  float4 pf[4];
  auto stage_load = [&](int s) {
    #pragma unroll
    for (int u = 0; u < 4; ++u) {
      if (srValid) pf[u] = *(const float4*)&wsi[wsiRow + (unsigned)(s * 64 + sc * 16 + u * 4)];
      else pf[u] = make_float4(0.f, 0.f, 0.f, 0.f);
    }
  };
  auto stage_write = [&](int buf) {
    unsigned p0 = pk2(pf[0].x, pf[0].y), p1 = pk2(pf[0].z, pf[0].w);
    unsigned p2 = pk2(pf[1].x, pf[1].y), p3 = pk2(pf[1].z, pf[1].w);
    unsigned p4 = pk2(pf[2].x, pf[2].y), p5 = pk2(pf[2].z, pf[2].w);
    unsigned p6 = pk2(pf[3].x, pf[3].y), p7 = pk2(pf[3].z, pf[3].w);
    char* base = (char*)&As[buf][0];
    *(uint4*)(base + (sraw ^ sswz))        = make_uint4(p0, p1, p2, p3);
    *(uint4*)(base + ((sraw + 16) ^ sswz)) = make_uint4(p4, p5, p6, p7);
  };

  // A-frag register prefetch buffers (static names, rule #20)
  bf16x8 afA[4], afB[4];
  #pragma unroll
  for (int mt = 0; mt < 4; ++mt) afA[mt] = *(const bf16x8*)(wpt + aBase[mt]); // (s=0,kc=0)

  // prologue: stage tile 0
  stage_load(0);
  stage_write(0);
  __syncthreads();

  // ---- phase 1: T = wsi @ Wp via MFMA, K=1024 in 16 steps of 64; 1 barrier/step ----
  for (int s = 0; s < 16; ++s) {
    const char* Ab = (const char*)&As[s & 1][0];
    if (s < 15) stage_load(s + 1);           // issue-early (T14)
    // kc = 0: prefetch kc=1 frags, compute with afA
    #pragma unroll
    for (int mt = 0; mt < 4; ++mt)
      afB[mt] = *(const bf16x8*)(wpt + (aBase[mt] + 64 * s + 32));
    {
      bf16x8 bfr[4];
      #pragma unroll
      for (int nt = 0; nt < 4; ++nt) {
        int row = l15 + 16 * nt;
        unsigned off = (unsigned)(row * 128 + lh * 16) ^ (unsigned)((row & 7) << 4);
        bfr[nt] = *(const bf16x8*)(Ab + off);
      }
      #pragma unroll
      for (int mt = 0; mt < 4; ++mt)
        #pragma unroll
        for (int nt = 0; nt < 4; ++nt)
          acc[mt][nt] = __builtin_amdgcn_mfma_f32_16x16x32_bf16(afA[mt], bfr[nt], acc[mt][nt], 0, 0, 0);
    }
    // kc = 1: prefetch (s+1,kc=0) frags, compute with afB
    if (s < 15) {
      #pragma unroll
      for (int mt = 0; mt < 4; ++mt)
        afA[mt] = *(const bf16x8*)(wpt + (aBase[mt] + 64 * (s + 1)));
    }
    {
      bf16x8 bfr[4];
      #pragma unroll
      for (int nt = 0; nt < 4; ++nt) {
        int row = l15 + 16 * nt;
        unsigned off = (unsigned)(row * 128 + lh * 16 + 64) ^ (unsigned)((row & 7) << 4);
        bfr[nt] = *(const bf16x8*)(Ab + off);
      }
      #pragma unroll
      for (int mt = 0; mt < 4; ++mt)
        #pragma unroll
        for (int nt = 0; nt < 4; ++nt)
          acc[mt][nt] = __builtin_amdgcn_mfma_f32_16x16x32_bf16(afB[mt], bfr[nt], acc[mt][nt], 0, 0, 0);
    }
    if (s < 15) stage_write((s + 1) & 1);    // write-late into the other buffer
    __syncthreads();
  }

  // ---- bias + LN1 ----
  float4 bp4[4], g4[4], b4[4];
  #pragma unroll
  for (int mt = 0; mt < 4; ++mt) {
    int m0 = 64 * wv + 16 * mt + 4 * lh;
    bp4[mt] = *(const float4*)&bp[m0];
    g4[mt]  = *(const float4*)&ln1_g[m0];
    b4[mt]  = *(const float4*)&ln1_b[m0];
  }
  float ps[4], pq[4];
  #pragma unroll
  for (int nt = 0; nt < 4; ++nt) { ps[nt] = 0.f; pq[nt] = 0.f; }
  #pragma unroll
  for (int mt = 0; mt < 4; ++mt) {
    const float bb4[4] = {bp4[mt].x, bp4[mt].y, bp4[mt].z, bp4[mt].w};
    #pragma unroll
    for (int nt = 0; nt < 4; ++nt)
      #pragma unroll
      for (int r = 0; r < 4; ++r) {
        float v = acc[mt][nt][r] + bb4[r];
        acc[mt][nt][r] = v;
        ps[nt] += v; pq[nt] += v * v;
      }
  }
  #pragma unroll
  for (int nt = 0; nt < 4; ++nt) {
    ps[nt] += __shfl_xor(ps[nt], 16); pq[nt] += __shfl_xor(pq[nt], 16);
    ps[nt] += __shfl_xor(ps[nt], 32); pq[nt] += __shfl_xor(pq[nt], 32);
  }
  if (lh == 0) {
    #pragma unroll
    for (int nt = 0; nt < 4; ++nt) {
      int row = l15 + 16 * nt;
      red[(wv * 64 + row) * 2]     = ps[nt];
      red[(wv * 64 + row) * 2 + 1] = pq[nt];
    }
  }
  __syncthreads();
  float mu[4], rstd[4];
  #pragma unroll
  for (int nt = 0; nt < 4; ++nt) {
    int row = l15 + 16 * nt;
    float s_ = 0.f, q_ = 0.f;
    #pragma unroll
    for (int w2 = 0; w2 < 4; ++w2) { s_ += red[(w2 * 64 + row) * 2]; q_ += red[(w2 * 64 + row) * 2 + 1]; }
    float m_ = s_ * (1.f / 256.f);
    float v_ = q_ * (1.f / 256.f) - m_ * m_;
    mu[nt] = m_; rstd[nt] = rsqrtf(v_ + LN_EPS);
  }
  #pragma unroll
  for (int nt = 0; nt < 4; ++nt) {
    int row = l15 + 16 * nt;
    unsigned rswz = (unsigned)((row & 7) << 4);
    #pragma unroll
    for (int mt = 0; mt < 4; ++mt) {
      float x0 = (acc[mt][nt][0] - mu[nt]) * rstd[nt] * g4[mt].x + b4[mt].x;
      float x1 = (acc[mt][nt][1] - mu[nt]) * rstd[nt] * g4[mt].y + b4[mt].y;
      float x2 = (acc[mt][nt][2] - mu[nt]) * rstd[nt] * g4[mt].z + b4[mt].z;
      float x3 = (acc[mt][nt][3] - mu[nt]) * rstd[nt] * g4[mt].w + b4[mt].w;
      unsigned p0 = pk2(x0, x1);
      unsigned p1 = pk2(x2, x3);
      int m0 = 64 * wv + 16 * mt + 4 * lh;
      unsigned off = (unsigned)(row * 512 + m0 * 2) ^ rswz;
      *(uint2*)((char*)Xn + off) = make_uint2(p0, p1);
    }
  }
  __syncthreads();

  // ---- phase 2: D2[m=kv-col][n=row] = WkvT(A) x xnT(B), K=256, with A prefetch ----
  f32x4 acc2[4][4];
  #pragma unroll
  for (int mt = 0; mt < 4; ++mt)
    #pragma unroll
    for (int nt = 0; nt < 4; ++nt) acc2[mt][nt] = z4;
  int a2Base[4];
  #pragma unroll
  for (int mt = 0; mt < 4; ++mt)
    a2Base[mt] = (64 * wv + 16 * mt + l15) * 256 + 8 * lh;

  bf16x8 gA[4], gB[4];
  #pragma unroll
  for (int mt = 0; mt < 4; ++mt) gA[mt] = *(const bf16x8*)(wkvt + a2Base[mt]); // kk=0

  #pragma unroll
  for (int kp = 0; kp < 4; ++kp) {
    const int kk0 = 2 * kp, kk1 = 2 * kp + 1;
    #pragma unroll
    for (int mt = 0; mt < 4; ++mt)
      gB[mt] = *(const bf16x8*)(wkvt + (a2Base[mt] + 32 * kk1));
    {
      bf16x8 bfr[4];
      #pragma unroll
      for (int nt = 0; nt < 4; ++nt) {
        int row = l15 + 16 * nt;
        unsigned off = (unsigned)(row * 512 + lh * 16 + kk0 * 64) ^ (unsigned)((row & 7) << 4);
        bfr[nt] = *(const bf16x8*)((const char*)Xn + off);
      }
      #pragma unroll
      for (int mt = 0; mt < 4; ++mt)
        #pragma unroll
        for (int nt = 0; nt < 4; ++nt)
          acc2[mt][nt] = __builtin_amdgcn_mfma_f32_16x16x32_bf16(gA[mt], bfr[nt], acc2[mt][nt], 0, 0, 0);
    }
    if (kp < 3) {
      #pragma unroll
      for (int mt = 0; mt < 4; ++mt)
        gA[mt] = *(const bf16x8*)(wkvt + (a2Base[mt] + 32 * (kk0 + 2)));
    }
    {
      bf16x8 bfr[4];
      #pragma unroll
      for (int nt = 0; nt < 4; ++nt) {
        int row = l15 + 16 * nt;
        unsigned off = (unsigned)(row * 512 + lh * 16 + kk1 * 64) ^ (unsigned)((row & 7) << 4);
        bfr[nt] = *(const bf16x8*)((const char*)Xn + off);
      }
      #pragma unroll
      for (int mt = 0; mt < 4; ++mt)
        #pragma unroll
        for (int nt = 0; nt < 4; ++nt)
          acc2[mt][nt] = __builtin_amdgcn_mfma_f32_16x16x32_bf16(gB[mt], bfr[nt], acc2[mt][nt], 0, 0, 0);
    }
  }

  float* part = ws + WS_PART + (size_t)b * PART_STRIDE;

  // ---- scores (waves 0,1 hold k-proj) ----
  if (wv < 2) {
    float4 qp4[4];
    #pragma unroll
    for (int mt = 0; mt < 4; ++mt)
      qp4[mt] = *(const float4*)&ws[WS_QP + 64 * wv + 16 * mt + 4 * lh];
    float sp[4];
    #pragma unroll
    for (int nt = 0; nt < 4; ++nt) {
      float s_ = 0.f;
      #pragma unroll
      for (int mt = 0; mt < 4; ++mt) {
        s_ = fmaf(qp4[mt].x, acc2[mt][nt][0], s_);
        s_ = fmaf(qp4[mt].y, acc2[mt][nt][1], s_);
        s_ = fmaf(qp4[mt].z, acc2[mt][nt][2], s_);
        s_ = fmaf(qp4[mt].w, acc2[mt][nt][3], s_);
      }
      sp[nt] = s_;
    }
    #pragma unroll
    for (int nt = 0; nt < 4; ++nt) {
      sp[nt] += __shfl_xor(sp[nt], 16);
      sp[nt] += __shfl_xor(sp[nt], 32);
    }
    if (lh == 0) {
      #pragma unroll
      for (int nt = 0; nt < 4; ++nt) red[wv * 64 + 16 * nt + l15] = sp[nt];
    }
  }
  __syncthreads();
  if (tid < 64) {
    int gr = r0 + tid;
    float s_ = red[tid] + red[64 + tid];
    if (gr >= N) s_ = -INFINITY;
    float mb = s_;
    #pragma unroll
    for (int m = 1; m < 64; m <<= 1) mb = fmaxf(mb, __shfl_xor(mb, m));
    float e = (gr < N) ? expf(s_ - mb) : 0.f;
    float l_ = e;
    #pragma unroll
    for (int m = 1; m < 64; m <<= 1) l_ += __shfl_xor(l_, m);
    wtsL[tid] = e;
    if (tid == 0) { part[PART_M] = mb; part[PART_L] = l_; }
  }
  __syncthreads();
  // ---- weighted-V partials (waves 2,3 hold v-proj) ----
  if (wv >= 2) {
    int wv2 = wv - 2;
    float wr[4];
    #pragma unroll
    for (int nt = 0; nt < 4; ++nt) wr[nt] = wtsL[16 * nt + l15];
    #pragma unroll
    for (int mt = 0; mt < 4; ++mt) {
      float vs0 = 0.f, vs1 = 0.f, vs2 = 0.f, vs3 = 0.f;
      #pragma unroll
      for (int nt = 0; nt < 4; ++nt) {
        vs0 = fmaf(wr[nt], acc2[mt][nt][0], vs0);
        vs1 = fmaf(wr[nt], acc2[mt][nt][1], vs1);
        vs2 = fmaf(wr[nt], acc2[mt][nt][2], vs2);
        vs3 = fmaf(wr[nt], acc2[mt][nt][3], vs3);
      }
      #pragma unroll
      for (int m = 1; m < 16; m <<= 1) {
        vs0 += __shfl_xor(vs0, m); vs1 += __shfl_xor(vs1, m);
        vs2 += __shfl_xor(vs2, m); vs3 += __shfl_xor(vs3, m);
      }
      if (l15 == 0)
        *(float4*)&part[64 * wv2 + 16 * mt + 4 * lh] = make_float4(vs0, vs1, vs2, vs3);
    }
  }
}

// ---------------- K_fin0: global max M, per-block weights, denominator L ----------------
__global__ __launch_bounds__(256) void k_fin0(float* __restrict__ ws, int NB)
{
  __shared__ float red[8];
  int tid = threadIdx.x, lane = tid & 63, wave = tid >> 6;
  const float* part = ws + WS_PART;
  float s0 = ws[WS_S0];

  float mloc = s0;
  for (int bb = tid; bb < NB; bb += 256) mloc = fmaxf(mloc, part[(size_t)bb * PART_STRIDE + PART_M]);
  for (int m = 1; m < 64; m <<= 1) mloc = fmaxf(mloc, __shfl_xor(mloc, m));
  if (lane == 0) red[wave] = mloc;
  __syncthreads();
  float M = fmaxf(fmaxf(red[0], red[1]), fmaxf(red[2], red[3]));

  float lp = 0.f;
  for (int bb = tid; bb < NB; bb += 256) {
    float w = expf(part[(size_t)bb * PART_STRIDE + PART_M] - M);
    ws[WS_WTS + bb] = w;
    lp = fmaf(part[(size_t)bb * PART_STRIDE + PART_L], w, lp);
  }
  for (int m = 1; m < 64; m <<= 1) lp += __shfl_xor(lp, m);
  __syncthreads();
  if (lane == 0) red[wave] = lp;
  __syncthreads();
  if (tid == 0) {
    float e0 = expf(s0 - M);
    ws[WS_LL] = red[0] + red[1] + red[2] + red[3] + e0;
    ws[WS_E0] = e0;
  }
}

// ---------------- K_fin1: 32-way parallel weighted partial combine ----------------
__global__ __launch_bounds__(128) void k_fin1(float* __restrict__ ws, int NB, int chunk)
{
  int g = blockIdx.x, col = threadIdx.x;
  int c0 = g * chunk, c1 = min(c0 + chunk, NB);
  const float* part = ws + WS_PART;
  const float* wts = ws + WS_WTS;
  float a = 0.f;
  #pragma unroll 4
  for (int bb = c0; bb < c1; ++bb)
    a = fmaf(part[(size_t)bb * PART_STRIDE + col], wts[bb], a);
  ws[WS_GP + g * 128 + col] = a;
}

// ---------------- K3: 2-row FFN head + logits/softmax ----------------
__global__ __launch_bounds__(256) void k_final(
    const float* __restrict__ ws,
    const float* __restrict__ Wf1, const float* __restrict__ bf1,
    const float* __restrict__ Wf2, const float* __restrict__ bf2,
    const float* __restrict__ ln2_g, const float* __restrict__ ln2_b,
    const float* __restrict__ ln3_g, const float* __restrict__ ln3_b,
    const float* __restrict__ Wl1, const float* __restrict__ bl1,
    const float* __restrict__ Wl2, const float* __restrict__ bl2,
    float* __restrict__ out)
{
  __shared__ float rowb[2][128];
  __shared__ float mmb[2][128];
  __shared__ float red[8];
  __shared__ float emb[256];
  __shared__ float abuf[64];
  __shared__ float lbuf[4];
  int tid = threadIdx.x, lane = tid & 63, wave = tid >> 6;

  if (tid < 128) {
    float v0 = ws[WS_V0 + tid];
    float a = v0 * ws[WS_E0];
    #pragma unroll
    for (int g = 0; g < NCOMB; ++g) a += ws[WS_GP + g * 128 + tid];
    rowb[0][tid] = a / ws[WS_LL];
    rowb[1][tid] = v0;
  }
  __syncthreads();

  int row = tid >> 7, k = tid & 127;
  float x = rowb[row][k];
  float ps = x, pq = x * x;
  for (int m = 1; m < 64; m <<= 1) { ps += __shfl_xor(ps, m); pq += __shfl_xor(pq, m); }
  __syncthreads();
  if (lane == 0) { red[wave] = ps; red[4 + wave] = pq; }
  __syncthreads();
  {
    float sum = red[row * 2] + red[row * 2 + 1];
    float sq  = red[4 + row * 2] + red[4 + row * 2 + 1];
    float mu = sum * (1.f / 128.f);
    float var = sq * (1.f / 128.f) - mu * mu;
    x = (x - mu) * rsqrtf(var + LN_EPS) * ln2_g[k] + ln2_b[k];
  }
  mmb[row][k] = x;
  __syncthreads();
  float t1 = bf1[k];
  for (int j = 0; j < 128; j++) t1 = fmaf(mmb[row][j], Wf1[j * 128 + k], t1);
  float gg = t1 * 0.5f * (1.f + erff(t1 * 0.70710678118654752f));
  __syncthreads();
  rowb[row][k] = gg;
  __syncthreads();
  float t2 = bf2[k];
  for (int j = 0; j < 128; j++) t2 = fmaf(rowb[row][j], Wf2[j * 128 + k], t2);
  ps = t2; pq = t2 * t2;
  for (int m = 1; m < 64; m <<= 1) { ps += __shfl_xor(ps, m); pq += __shfl_xor(pq, m); }
  __syncthreads();
  if (lane == 0) { red[wave] = ps; red[4 + wave] = pq; }
  __syncthreads();
  {
    float sum = red[row * 2] + red[row * 2 + 1];
    float sq  = red[4 + row * 2] + red[4 + row * 2 + 1];
    float mu = sum * (1.f / 128.f);
    float var = sq * (1.f / 128.f) - mu * mu;
    t2 = (t2 - mu) * rsqrtf(var + LN_EPS) * ln3_g[k] + ln3_b[k];
  }
  emb[row * 128 + k] = t2;
  __syncthreads();
  if (tid < 64) {
    float a = bl1[tid];
    for (int j = 0; j < 256; j++) a = fmaf(emb[j], Wl1[j * 64 + tid], a);
    abuf[tid] = fmaxf(a, 0.f);
  }
  __syncthreads();
  if (tid < 4) {
    float lg = bl2[tid];
    for (int j = 0; j < 64; j++) lg = fmaf(abuf[j], Wl2[j * 4 + tid], lg);
    lbuf[tid] = lg;
  }
  __syncthreads();
  if (tid < 4) {
    float m4 = fmaxf(fmaxf(lbuf[0], lbuf[1]), fmaxf(lbuf[2], lbuf[3]));
    float e0 = expf(lbuf[0] - m4), e1 = expf(lbuf[1] - m4);
    float e2 = expf(lbuf[2] - m4), e3 = expf(lbuf[3] - m4);
    float ssum = e0 + e1 + e2 + e3;
    out[tid] = lbuf[tid];
    out[4 + tid] = expf(lbuf[tid] - m4) / ssum;
  }
}

extern "C" void kernel_launch(void* const* d_in, const int* in_sizes, int n_in,
                              void* d_out, int out_size, void* d_ws, size_t ws_size,
                              hipStream_t stream) {
  const float* wsi    = (const float*)d_in[0];
  const float* x_omic = (const float*)d_in[1];
  const float* W1     = (const float*)d_in[2];
  const float* b1     = (const float*)d_in[3];
  const float* W2     = (const float*)d_in[4];
  const float* b2     = (const float*)d_in[5];
  const float* Wp     = (const float*)d_in[6];
  const float* bp     = (const float*)d_in[7];
  const float* ln1_g  = (const float*)d_in[8];
  const float* ln1_b  = (const float*)d_in[9];
  const float* Wqkv   = (const float*)d_in[10];
  const float* ln2_g  = (const float*)d_in[11];
  const float* ln2_b  = (const float*)d_in[12];
  const float* Wf1    = (const float*)d_in[13];
  const float* bf1    = (const float*)d_in[14];
  const float* Wf2    = (const float*)d_in[15];
  const float* bf2    = (const float*)d_in[16];
  const float* ln3_g  = (const float*)d_in[17];
  const float* ln3_b  = (const float*)d_in[18];
  const float* Wl1    = (const float*)d_in[19];
  const float* bl1    = (const float*)d_in[20];
  const float* Wl2    = (const float*)d_in[21];
  const float* bl2    = (const float*)d_in[22];
  float* ws   = (float*)d_ws;
  float* outp = (float*)d_out;
  ushortT* wpt  = (ushortT*)(ws + WS_WPT);
  ushortT* wkvt = (ushortT*)(ws + WS_WKVT);

  int N = in_sizes[0] / 1024;
  int d_omic = in_sizes[1];
  int NB = (N + 63) / 64;
  int chunk = (NB + NCOMB - 1) / NCOMB;

  k_prep<<<512, 256, 0, stream>>>(Wp, Wqkv, wpt, wkvt);
  k_h1<<<16, 256, 0, stream>>>(x_omic, W1, d_omic, ws);
  k_omic<<<1, 256, 0, stream>>>(b1, W2, b2, Wqkv, ln1_g, ln1_b, ws);
  k_main<<<NB, 256, 0, stream>>>(wsi, N, wpt, wkvt, bp, ln1_g, ln1_b, ws);
  k_fin0<<<1, 256, 0, stream>>>(ws, NB);
  k_fin1<<<NCOMB, 128, 0, stream>>>(ws, NB, chunk);
  k_final<<<1, 256, 0, stream>>>(ws, Wf1, bf1, Wf2, bf2, ln2_g, ln2_b,
                                 ln3_g, ln3_b, Wl1, bl1, Wl2, bl2, outp);
}

// Round 4
// 160.289 us; speedup vs baseline: 3.9220x; 1.1717x over previous
//
#include <hip/hip_runtime.h>
#include <hip/hip_bf16.h>
#include <math.h>

#define LN_EPS 1e-5f

typedef unsigned short ushortT;
typedef short bf16x8 __attribute__((ext_vector_type(8)));
typedef float f32x4 __attribute__((ext_vector_type(4)));

// ws layout (float offsets)
#define WS_QP   0            // q_p * scale (128)
#define WS_V0   128          // v0 (128)
#define WS_S0   256          // s0 scalar
#define WS_LL   258          // softmax denominator L
#define WS_E0   259          // exp(s0 - M)
#define WS_H1P  512          // 16*256 h1 partials
#define WS_PART 4608         // per-block partials: [acc 128][m][l][pad] stride 132
#define PART_STRIDE 132
#define PART_M 128
#define PART_L 129
#define WS_WTS  108000       // per-block softmax weights (NB floats)
#define WS_GP   109000       // 32 x 128 combiner partial sums
#define NCOMB   32
#define WS_WPT  131072       // ushort region: WpT[256][1024] bf16 (512KB)
#define WS_WKVT 262144       // ushort region: WkvT[256][256] bf16 (128KB)

__device__ __forceinline__ float elu1(float x){ return x > 0.f ? x : expm1f(x); }
__device__ __forceinline__ unsigned short f2bf(float x){
  unsigned u = __float_as_uint(x);
  return (unsigned short)((u + 0x7fffu + ((u >> 16) & 1u)) >> 16);
}
__device__ __forceinline__ unsigned pk2(float lo, float hi){
  union { __hip_bfloat162 h; unsigned u; } cv;
  cv.h = __float22bfloat162_rn(make_float2(lo, hi));
  return cv.u;
}
// async global->LDS DMA, 16B/lane, linear dest (base + lane*16)
__device__ __forceinline__ void dma16(const void* g, void* l) {
  __builtin_amdgcn_global_load_lds(
      (const __attribute__((address_space(1))) unsigned int*)g,
      (__attribute__((address_space(3))) unsigned int*)l, 16, 0, 0);
}

// ---------------- K_prep: transpose+convert Wp and Wqkv(k|v) to bf16 ----------------
// Coalesced reads (row-major source), 8B scattered writes.
__global__ __launch_bounds__(256) void k_prep(const float* __restrict__ Wp,
    const float* __restrict__ Wqkv, ushortT* __restrict__ wpt, ushortT* __restrict__ wkvt)
{
  int bb = blockIdx.x, t = threadIdx.x;
  if (bb < 256) {
    int k0 = bb * 4;
    unsigned lo, hi;
    lo = (unsigned)f2bf(Wp[(size_t)(k0 + 0) * 256 + t]) |
         ((unsigned)f2bf(Wp[(size_t)(k0 + 1) * 256 + t]) << 16);
    hi = (unsigned)f2bf(Wp[(size_t)(k0 + 2) * 256 + t]) |
         ((unsigned)f2bf(Wp[(size_t)(k0 + 3) * 256 + t]) << 16);
    *(uint2*)&wpt[t * 1024 + k0] = make_uint2(lo, hi);
  } else {
    int k0 = (bb - 256) * 4;
    unsigned lo, hi;
    lo = (unsigned)f2bf(Wqkv[(size_t)(k0 + 0) * 384 + 128 + t]) |
         ((unsigned)f2bf(Wqkv[(size_t)(k0 + 1) * 384 + 128 + t]) << 16);
    hi = (unsigned)f2bf(Wqkv[(size_t)(k0 + 2) * 384 + 128 + t]) |
         ((unsigned)f2bf(Wqkv[(size_t)(k0 + 3) * 384 + 128 + t]) << 16);
    *(uint2*)&wkvt[t * 256 + k0] = make_uint2(lo, hi);
  }
}

// ---------------- K0: h1 partial dots ----------------
__global__ __launch_bounds__(256) void k_h1(const float* __restrict__ x,
    const float* __restrict__ W1, int d_omic, float* __restrict__ ws)
{
  int g = blockIdx.x, tid = threadIdx.x;
  int i0 = g * 99, i1 = min(i0 + 99, d_omic);
  __shared__ float xs[112];
  for (int i = i0 + tid; i < i1; i += 256) xs[i - i0] = x[i];
  __syncthreads();
  float s = 0.f;
  for (int i = i0; i < i1; i++) s = fmaf(xs[i - i0], W1[(size_t)i * 256 + tid], s);
  ws[WS_H1P + g * 256 + tid] = s;
}

// ---------------- K1: omic MLP + token0 LN1 + q_p/k_p/v0 + s0 (exact fp32) ----------------
__global__ __launch_bounds__(256) void k_omic(
    const float* __restrict__ b1,
    const float* __restrict__ W2, const float* __restrict__ b2,
    const float* __restrict__ Wqkv,
    const float* __restrict__ ln1_g, const float* __restrict__ ln1_b,
    float* __restrict__ ws)
{
  __shared__ float h1[256];
  __shared__ float xn0[256];
  __shared__ float qs[128], ks[128];
  __shared__ float red[8];
  int tid = threadIdx.x, lane = tid & 63, wave = tid >> 6;

  float s = b1[tid];
  for (int g = 0; g < 16; g++) s += ws[WS_H1P + g * 256 + tid];
  h1[tid] = elu1(s);
  __syncthreads();

  s = b2[tid];
  for (int i = 0; i < 256; i++) s = fmaf(h1[i], W2[i * 256 + tid], s);
  float t0 = elu1(s);

  float ps = t0, pq = t0 * t0;
  for (int m = 1; m < 64; m <<= 1) { ps += __shfl_xor(ps, m); pq += __shfl_xor(pq, m); }
  if (lane == 0) { red[wave] = ps; red[4 + wave] = pq; }
  __syncthreads();
  float mu = (red[0] + red[1] + red[2] + red[3]) * (1.f / 256.f);
  float var = (red[4] + red[5] + red[6] + red[7]) * (1.f / 256.f) - mu * mu;
  float xn = (t0 - mu) * rsqrtf(var + LN_EPS) * ln1_g[tid] + ln1_b[tid];
  xn0[tid] = xn;
  __syncthreads();

  float a = 0.f;
  for (int j = 0; j < 256; j++) a = fmaf(xn0[j], Wqkv[j * 384 + tid], a);
  if (tid < 128) { float q = a * 0.088388347648318447f; qs[tid] = q; ws[WS_QP + tid] = q; }
  else           { ks[tid - 128] = a; }
  if (tid < 128) {
    float av = 0.f;
    for (int j = 0; j < 256; j++) av = fmaf(xn0[j], Wqkv[j * 384 + 256 + tid], av);
    ws[WS_V0 + tid] = av;
  }
  __syncthreads();
  float p = (tid < 128) ? qs[tid] * ks[tid] : 0.f;
  for (int m = 1; m < 64; m <<= 1) p += __shfl_xor(p, m);
  if (lane == 0) red[wave] = p;
  __syncthreads();
  if (tid == 0) ws[WS_S0] = red[0] + red[1] + red[2] + red[3];
}

// ---------------- K2: MFMA fused wsi@Wp -> LN1 -> [k|v] -> scores -> partials ----------------
// All operand streams staged via global_load_lds (linear dest + inverse-swizzled source).
// D1[m=Wp-outcol][n=wsi-row] = WpT(A) x wsiT(B); C/D lane layout m89-verified.
__global__ __launch_bounds__(256, 3) void k_main(
    const float* __restrict__ wsi, int N,
    const ushortT* __restrict__ wpt, const ushortT* __restrict__ wkvt,
    const float* __restrict__ bp,
    const float* __restrict__ ln1_g, const float* __restrict__ ln1_b,
    float* __restrict__ ws)
{
  __shared__ __align__(16) char R1[16384];  // phase1: wsi fp32 tile / LN red / phase2: wkvt slice
  __shared__ __align__(16) char R2[32768];  // phase1: wpt slice / phase2: Xn (bf16, swizzled)
  __shared__ float wtsL[64];

  const int tid = threadIdx.x;
  const int lane = tid & 63, wv = tid >> 6;
  const int l15 = lane & 15, lh = lane >> 4;
  const int b = blockIdx.x, r0 = b * 64;

  // ---- per-lane DMA source offsets (inverse-swizzled) ----
  // wsi tile: [row][64 floats], swizzle on 32B units: u' = u ^ (row&7)
  int wgoff[4];
  #pragma unroll
  for (int i = 0; i < 4; ++i) {
    int row = 16 * wv + 4 * i + (lane >> 4);
    int c16 = lane & 15;
    int c16g = (((c16 >> 1) ^ (row & 7)) << 1) | (c16 & 1);
    int gr = r0 + row; gr = (gr < N) ? gr : (N - 1);   // clamp; zeroed on read
    wgoff[i] = gr * 1024 + c16g * 4;
  }
  // wpt slice: [m][64 bf16] rows of 128B = 8x16B chunks; chunk' = chunk ^ (m&7)
  const int pbase = (64 * wv + (lane >> 3)) * 1024 + (((lane & 7) ^ ((lane >> 3) & 7)) * 8);
  // wkvt slice: [m][32 bf16] rows of 64B = 4x16B chunks; chunk' = chunk ^ (m&3)
  const int kbase = (64 * wv + (lane >> 2)) * 256 + (((lane & 3) ^ ((lane >> 2) & 3)) * 8);

  const f32x4 z4 = {0.f, 0.f, 0.f, 0.f};
  f32x4 acc[4][4];
  #pragma unroll
  for (int mt = 0; mt < 4; ++mt)
    #pragma unroll
    for (int nt = 0; nt < 4; ++nt) acc[mt][nt] = z4;

  bool rowbad[4];
  #pragma unroll
  for (int nt = 0; nt < 4; ++nt) rowbad[nt] = (r0 + l15 + 16 * nt) >= N;

  // ---- prologue: stage tile 0 ----
  #pragma unroll
  for (int i = 0; i < 4; ++i) dma16(wsi + wgoff[i], R1 + (16 * wv + 4 * i) * 256);
  #pragma unroll
  for (int i = 0; i < 8; ++i) dma16(wpt + pbase + i * 8192, R2 + (64 * wv + 8 * i) * 128);
  __syncthreads();

  // ---- phase 1: T = wsi @ Wp, K=1024 in 16 steps of 64 ----
  for (int s = 0; s < 16; ++s) {
    #pragma unroll
    for (int kc = 0; kc < 2; ++kc) {
      bf16x8 af[4], bfr[4];
      #pragma unroll
      for (int mt = 0; mt < 4; ++mt)
        af[mt] = *(const bf16x8*)(R2 + (64 * wv + 16 * mt + l15) * 128 +
                                  (((lh + 4 * kc) ^ (l15 & 7)) << 4));
      #pragma unroll
      for (int nt = 0; nt < 4; ++nt) {
        int row = l15 + 16 * nt;
        const char* p = R1 + row * 256 + (((lh + 4 * kc) ^ (row & 7)) << 5);
        uint4 ua = *(const uint4*)p;
        uint4 ub = *(const uint4*)(p + 16);
        if (rowbad[nt]) { ua = make_uint4(0,0,0,0); ub = make_uint4(0,0,0,0); }
        union { unsigned u[4]; bf16x8 v; } cv;
        cv.u[0] = pk2(__uint_as_float(ua.x), __uint_as_float(ua.y));
        cv.u[1] = pk2(__uint_as_float(ua.z), __uint_as_float(ua.w));
        cv.u[2] = pk2(__uint_as_float(ub.x), __uint_as_float(ub.y));
        cv.u[3] = pk2(__uint_as_float(ub.z), __uint_as_float(ub.w));
        bfr[nt] = cv.v;
      }
      #pragma unroll
      for (int mt = 0; mt < 4; ++mt)
        #pragma unroll
        for (int nt = 0; nt < 4; ++nt)
          acc[mt][nt] = __builtin_amdgcn_mfma_f32_16x16x32_bf16(af[mt], bfr[nt], acc[mt][nt], 0, 0, 0);
    }
    __syncthreads();                        // all reads of this tile done
    if (s < 15) {
      #pragma unroll
      for (int i = 0; i < 4; ++i)
        dma16(wsi + wgoff[i] + (s + 1) * 64, R1 + (16 * wv + 4 * i) * 256);
      #pragma unroll
      for (int i = 0; i < 8; ++i)
        dma16(wpt + pbase + i * 8192 + (s + 1) * 64, R2 + (64 * wv + 8 * i) * 128);
    }
    __syncthreads();                        // vmcnt drained -> next tile ready
  }

  // ---- bias + LN1 ----
  float* red = (float*)R1;                  // R1 free after phase 1
  float4 bp4[4], g4[4], b4[4];
  #pragma unroll
  for (int mt = 0; mt < 4; ++mt) {
    int m0 = 64 * wv + 16 * mt + 4 * lh;
    bp4[mt] = *(const float4*)&bp[m0];
    g4[mt]  = *(const float4*)&ln1_g[m0];
    b4[mt]  = *(const float4*)&ln1_b[m0];
  }
  float ps[4], pq[4];
  #pragma unroll
  for (int nt = 0; nt < 4; ++nt) { ps[nt] = 0.f; pq[nt] = 0.f; }
  #pragma unroll
  for (int mt = 0; mt < 4; ++mt) {
    const float bb4[4] = {bp4[mt].x, bp4[mt].y, bp4[mt].z, bp4[mt].w};
    #pragma unroll
    for (int nt = 0; nt < 4; ++nt)
      #pragma unroll
      for (int r = 0; r < 4; ++r) {
        float v = acc[mt][nt][r] + bb4[r];
        acc[mt][nt][r] = v;
        ps[nt] += v; pq[nt] += v * v;
      }
  }
  #pragma unroll
  for (int nt = 0; nt < 4; ++nt) {
    ps[nt] += __shfl_xor(ps[nt], 16); pq[nt] += __shfl_xor(pq[nt], 16);
    ps[nt] += __shfl_xor(ps[nt], 32); pq[nt] += __shfl_xor(pq[nt], 32);
  }
  if (lh == 0) {
    #pragma unroll
    for (int nt = 0; nt < 4; ++nt) {
      int row = l15 + 16 * nt;
      red[(wv * 64 + row) * 2]     = ps[nt];
      red[(wv * 64 + row) * 2 + 1] = pq[nt];
    }
  }
  __syncthreads();
  float mu[4], rstd[4];
  #pragma unroll
  for (int nt = 0; nt < 4; ++nt) {
    int row = l15 + 16 * nt;
    float s_ = 0.f, q_ = 0.f;
    #pragma unroll
    for (int w2 = 0; w2 < 4; ++w2) { s_ += red[(w2 * 64 + row) * 2]; q_ += red[(w2 * 64 + row) * 2 + 1]; }
    float m_ = s_ * (1.f / 256.f);
    float v_ = q_ * (1.f / 256.f) - m_ * m_;
    mu[nt] = m_; rstd[nt] = rsqrtf(v_ + LN_EPS);
  }
  // write xn (bf16, swizzled [row][col]) into R2
  #pragma unroll
  for (int nt = 0; nt < 4; ++nt) {
    int row = l15 + 16 * nt;
    unsigned rswz = (unsigned)((row & 7) << 4);
    #pragma unroll
    for (int mt = 0; mt < 4; ++mt) {
      float x0 = (acc[mt][nt][0] - mu[nt]) * rstd[nt] * g4[mt].x + b4[mt].x;
      float x1 = (acc[mt][nt][1] - mu[nt]) * rstd[nt] * g4[mt].y + b4[mt].y;
      float x2 = (acc[mt][nt][2] - mu[nt]) * rstd[nt] * g4[mt].z + b4[mt].z;
      float x3 = (acc[mt][nt][3] - mu[nt]) * rstd[nt] * g4[mt].w + b4[mt].w;
      unsigned p0 = pk2(x0, x1);
      unsigned p1 = pk2(x2, x3);
      int m0 = 64 * wv + 16 * mt + 4 * lh;
      unsigned off = (unsigned)(row * 512 + m0 * 2) ^ rswz;
      *(uint2*)(R2 + off) = make_uint2(p0, p1);
    }
  }

  // ---- phase 2: D2[m=kv-col][n=row] = WkvT(A) x xnT(B), K=256 in 8 slices of 32 ----
  f32x4 acc2[4][4];
  #pragma unroll
  for (int mt = 0; mt < 4; ++mt)
    #pragma unroll
    for (int nt = 0; nt < 4; ++nt) acc2[mt][nt] = z4;

  for (int kk = 0; kk < 8; ++kk) {
    __syncthreads();   // prev slice reads done (iter0: Xn visible, red reads done)
    #pragma unroll
    for (int i = 0; i < 4; ++i)
      dma16(wkvt + kbase + i * 4096 + kk * 32, R1 + (64 * wv + 16 * i) * 64);
    __syncthreads();   // slice ready
    bf16x8 af[4], bfr[4];
    #pragma unroll
    for (int mt = 0; mt < 4; ++mt)
      af[mt] = *(const bf16x8*)(R1 + (64 * wv + 16 * mt + l15) * 64 + ((lh ^ (l15 & 3)) << 4));
    #pragma unroll
    for (int nt = 0; nt < 4; ++nt) {
      int row = l15 + 16 * nt;
      unsigned off = (unsigned)(row * 512 + lh * 16 + kk * 64) ^ (unsigned)((row & 7) << 4);
      bfr[nt] = *(const bf16x8*)(R2 + off);
    }
    #pragma unroll
    for (int mt = 0; mt < 4; ++mt)
      #pragma unroll
      for (int nt = 0; nt < 4; ++nt)
        acc2[mt][nt] = __builtin_amdgcn_mfma_f32_16x16x32_bf16(af[mt], bfr[nt], acc2[mt][nt], 0, 0, 0);
  }
  __syncthreads();     // R1 reads done; reuse as red for scores

  float* part = ws + WS_PART + (size_t)b * PART_STRIDE;

  // ---- scores (waves 0,1 hold k-proj) ----
  if (wv < 2) {
    float4 qp4[4];
    #pragma unroll
    for (int mt = 0; mt < 4; ++mt)
      qp4[mt] = *(const float4*)&ws[WS_QP + 64 * wv + 16 * mt + 4 * lh];
    float sp[4];
    #pragma unroll
    for (int nt = 0; nt < 4; ++nt) {
      float s_ = 0.f;
      #pragma unroll
      for (int mt = 0; mt < 4; ++mt) {
        s_ = fmaf(qp4[mt].x, acc2[mt][nt][0], s_);
        s_ = fmaf(qp4[mt].y, acc2[mt][nt][1], s_);
        s_ = fmaf(qp4[mt].z, acc2[mt][nt][2], s_);
        s_ = fmaf(qp4[mt].w, acc2[mt][nt][3], s_);
      }
      sp[nt] = s_;
    }
    #pragma unroll
    for (int nt = 0; nt < 4; ++nt) {
      sp[nt] += __shfl_xor(sp[nt], 16);
      sp[nt] += __shfl_xor(sp[nt], 32);
    }
    if (lh == 0) {
      #pragma unroll
      for (int nt = 0; nt < 4; ++nt) red[wv * 64 + 16 * nt + l15] = sp[nt];
    }
  }
  __syncthreads();
  if (tid < 64) {
    int gr = r0 + tid;
    float s_ = red[tid] + red[64 + tid];
    if (gr >= N) s_ = -INFINITY;
    float mb = s_;
    #pragma unroll
    for (int m = 1; m < 64; m <<= 1) mb = fmaxf(mb, __shfl_xor(mb, m));
    float e = (gr < N) ? expf(s_ - mb) : 0.f;
    float l_ = e;
    #pragma unroll
    for (int m = 1; m < 64; m <<= 1) l_ += __shfl_xor(l_, m);
    wtsL[tid] = e;
    if (tid == 0) { part[PART_M] = mb; part[PART_L] = l_; }
  }
  __syncthreads();
  // ---- weighted-V partials (waves 2,3 hold v-proj) ----
  if (wv >= 2) {
    int wv2 = wv - 2;
    float wr[4];
    #pragma unroll
    for (int nt = 0; nt < 4; ++nt) wr[nt] = wtsL[16 * nt + l15];
    #pragma unroll
    for (int mt = 0; mt < 4; ++mt) {
      float vs0 = 0.f, vs1 = 0.f, vs2 = 0.f, vs3 = 0.f;
      #pragma unroll
      for (int nt = 0; nt < 4; ++nt) {
        vs0 = fmaf(wr[nt], acc2[mt][nt][0], vs0);
        vs1 = fmaf(wr[nt], acc2[mt][nt][1], vs1);
        vs2 = fmaf(wr[nt], acc2[mt][nt][2], vs2);
        vs3 = fmaf(wr[nt], acc2[mt][nt][3], vs3);
      }
      #pragma unroll
      for (int m = 1; m < 16; m <<= 1) {
        vs0 += __shfl_xor(vs0, m); vs1 += __shfl_xor(vs1, m);
        vs2 += __shfl_xor(vs2, m); vs3 += __shfl_xor(vs3, m);
      }
      if (l15 == 0)
        *(float4*)&part[64 * wv2 + 16 * mt + 4 * lh] = make_float4(vs0, vs1, vs2, vs3);
    }
  }
}

// ---------------- K_fin0: global max M, per-block weights, denominator L ----------------
__global__ __launch_bounds__(256) void k_fin0(float* __restrict__ ws, int NB)
{
  __shared__ float red[8];
  int tid = threadIdx.x, lane = tid & 63, wave = tid >> 6;
  const float* part = ws + WS_PART;
  float s0 = ws[WS_S0];

  float mloc = s0;
  for (int bb = tid; bb < NB; bb += 256) mloc = fmaxf(mloc, part[(size_t)bb * PART_STRIDE + PART_M]);
  for (int m = 1; m < 64; m <<= 1) mloc = fmaxf(mloc, __shfl_xor(mloc, m));
  if (lane == 0) red[wave] = mloc;
  __syncthreads();
  float M = fmaxf(fmaxf(red[0], red[1]), fmaxf(red[2], red[3]));

  float lp = 0.f;
  for (int bb = tid; bb < NB; bb += 256) {
    float w = expf(part[(size_t)bb * PART_STRIDE + PART_M] - M);
    ws[WS_WTS + bb] = w;
    lp = fmaf(part[(size_t)bb * PART_STRIDE + PART_L], w, lp);
  }
  for (int m = 1; m < 64; m <<= 1) lp += __shfl_xor(lp, m);
  __syncthreads();
  if (lane == 0) red[wave] = lp;
  __syncthreads();
  if (tid == 0) {
    float e0 = expf(s0 - M);
    ws[WS_LL] = red[0] + red[1] + red[2] + red[3] + e0;
    ws[WS_E0] = e0;
  }
}

// ---------------- K_fin1: 32-way parallel weighted partial combine ----------------
__global__ __launch_bounds__(128) void k_fin1(float* __restrict__ ws, int NB, int chunk)
{
  int g = blockIdx.x, col = threadIdx.x;
  int c0 = g * chunk, c1 = min(c0 + chunk, NB);
  const float* part = ws + WS_PART;
  const float* wts = ws + WS_WTS;
  float a = 0.f;
  #pragma unroll 4
  for (int bb = c0; bb < c1; ++bb)
    a = fmaf(part[(size_t)bb * PART_STRIDE + col], wts[bb], a);
  ws[WS_GP + g * 128 + col] = a;
}

// ---------------- K3: 2-row FFN head + logits/softmax ----------------
__global__ __launch_bounds__(256) void k_final(
    const float* __restrict__ ws,
    const float* __restrict__ Wf1, const float* __restrict__ bf1,
    const float* __restrict__ Wf2, const float* __restrict__ bf2,
    const float* __restrict__ ln2_g, const float* __restrict__ ln2_b,
    const float* __restrict__ ln3_g, const float* __restrict__ ln3_b,
    const float* __restrict__ Wl1, const float* __restrict__ bl1,
    const float* __restrict__ Wl2, const float* __restrict__ bl2,
    float* __restrict__ out)
{
  __shared__ float rowb[2][128];
  __shared__ float mmb[2][128];
  __shared__ float red[8];
  __shared__ float emb[256];
  __shared__ float abuf[64];
  __shared__ float lbuf[4];
  int tid = threadIdx.x, lane = tid & 63, wave = tid >> 6;

  if (tid < 128) {
    float v0 = ws[WS_V0 + tid];
    float a = v0 * ws[WS_E0];
    #pragma unroll
    for (int g = 0; g < NCOMB; ++g) a += ws[WS_GP + g * 128 + tid];
    rowb[0][tid] = a / ws[WS_LL];
    rowb[1][tid] = v0;
  }
  __syncthreads();

  int row = tid >> 7, k = tid & 127;
  float x = rowb[row][k];
  float ps = x, pq = x * x;
  for (int m = 1; m < 64; m <<= 1) { ps += __shfl_xor(ps, m); pq += __shfl_xor(pq, m); }
  __syncthreads();
  if (lane == 0) { red[wave] = ps; red[4 + wave] = pq; }
  __syncthreads();
  {
    float sum = red[row * 2] + red[row * 2 + 1];
    float sq  = red[4 + row * 2] + red[4 + row * 2 + 1];
    float mu = sum * (1.f / 128.f);
    float var = sq * (1.f / 128.f) - mu * mu;
    x = (x - mu) * rsqrtf(var + LN_EPS) * ln2_g[k] + ln2_b[k];
  }
  mmb[row][k] = x;
  __syncthreads();
  float t1 = bf1[k];
  for (int j = 0; j < 128; j++) t1 = fmaf(mmb[row][j], Wf1[j * 128 + k], t1);
  float gg = t1 * 0.5f * (1.f + erff(t1 * 0.70710678118654752f));
  __syncthreads();
  rowb[row][k] = gg;
  __syncthreads();
  float t2 = bf2[k];
  for (int j = 0; j < 128; j++) t2 = fmaf(rowb[row][j], Wf2[j * 128 + k], t2);
  ps = t2; pq = t2 * t2;
  for (int m = 1; m < 64; m <<= 1) { ps += __shfl_xor(ps, m); pq += __shfl_xor(pq, m); }
  __syncthreads();
  if (lane == 0) { red[wave] = ps; red[4 + wave] = pq; }
  __syncthreads();
  {
    float sum = red[row * 2] + red[row * 2 + 1];
    float sq  = red[4 + row * 2] + red[4 + row * 2 + 1];
    float mu = sum * (1.f / 128.f);
    float var = sq * (1.f / 128.f) - mu * mu;
    t2 = (t2 - mu) * rsqrtf(var + LN_EPS) * ln3_g[k] + ln3_b[k];
  }
  emb[row * 128 + k] = t2;
  __syncthreads();
  if (tid < 64) {
    float a = bl1[tid];
    for (int j = 0; j < 256; j++) a = fmaf(emb[j], Wl1[j * 64 + tid], a);
    abuf[tid] = fmaxf(a, 0.f);
  }
  __syncthreads();
  if (tid < 4) {
    float lg = bl2[tid];
    for (int j = 0; j < 64; j++) lg = fmaf(abuf[j], Wl2[j * 4 + tid], lg);
    lbuf[tid] = lg;
  }
  __syncthreads();
  if (tid < 4) {
    float m4 = fmaxf(fmaxf(lbuf[0], lbuf[1]), fmaxf(lbuf[2], lbuf[3]));
    float e0 = expf(lbuf[0] - m4), e1 = expf(lbuf[1] - m4);
    float e2 = expf(lbuf[2] - m4), e3 = expf(lbuf[3] - m4);
    float ssum = e0 + e1 + e2 + e3;
    out[tid] = lbuf[tid];
    out[4 + tid] = expf(lbuf[tid] - m4) / ssum;
  }
}

extern "C" void kernel_launch(void* const* d_in, const int* in_sizes, int n_in,
                              void* d_out, int out_size, void* d_ws, size_t ws_size,
                              hipStream_t stream) {
  const float* wsi    = (const float*)d_in[0];
  const float* x_omic = (const float*)d_in[1];
  const float* W1     = (const float*)d_in[2];
  const float* b1     = (const float*)d_in[3];
  const float* W2     = (const float*)d_in[4];
  const float* b2     = (const float*)d_in[5];
  const float* Wp     = (const float*)d_in[6];
  const float* bp     = (const float*)d_in[7];
  const float* ln1_g  = (const float*)d_in[8];
  const float* ln1_b  = (const float*)d_in[9];
  const float* Wqkv   = (const float*)d_in[10];
  const float* ln2_g  = (const float*)d_in[11];
  const float* ln2_b  = (const float*)d_in[12];
  const float* Wf1    = (const float*)d_in[13];
  const float* bf1    = (const float*)d_in[14];
  const float* Wf2    = (const float*)d_in[15];
  const float* bf2    = (const float*)d_in[16];
  const float* ln3_g  = (const float*)d_in[17];
  const float* ln3_b  = (const float*)d_in[18];
  const float* Wl1    = (const float*)d_in[19];
  const float* bl1    = (const float*)d_in[20];
  const float* Wl2    = (const float*)d_in[21];
  const float* bl2    = (const float*)d_in[22];
  float* ws   = (float*)d_ws;
  float* outp = (float*)d_out;
  ushortT* wpt  = (ushortT*)(ws + WS_WPT);
  ushortT* wkvt = (ushortT*)(ws + WS_WKVT);

  int N = in_sizes[0] / 1024;
  int d_omic = in_sizes[1];
  int NB = (N + 63) / 64;
  int chunk = (NB + NCOMB - 1) / NCOMB;

  k_prep<<<320, 256, 0, stream>>>(Wp, Wqkv, wpt, wkvt);
  k_h1<<<16, 256, 0, stream>>>(x_omic, W1, d_omic, ws);
  k_omic<<<1, 256, 0, stream>>>(b1, W2, b2, Wqkv, ln1_g, ln1_b, ws);
  k_main<<<NB, 256, 0, stream>>>(wsi, N, wpt, wkvt, bp, ln1_g, ln1_b, ws);
  k_fin0<<<1, 256, 0, stream>>>(ws, NB);
  k_fin1<<<NCOMB, 128, 0, stream>>>(ws, NB, chunk);
  k_final<<<1, 256, 0, stream>>>(ws, Wf1, bf1, Wf2, bf2, ln2_g, ln2_b,
                                 ln3_g, ln3_b, Wl1, bl1, Wl2, bl2, outp);
}